// Round 11
// baseline (371.148 us; speedup 1.0000x reference)
//
#include <hip/hip_runtime.h>

// DoubleAttention: B=1024, S_OUT=30, S_IN=17, D_IN=3, H=4
// Round 11: fc1 gets fc2's proven recipe: block-level K-split-3 (6144 blocks,
// 5-iter wave loops) -> f16 partials + separate tanh/bias reduce kernel.
// Cross-round evidence: fc1 variants all pinned at ~1 TB/s L2-miss (1 load
// in flight per latency); fc2's many-block short-loop shape ran ~2.5-3 TB/s.
//
// ws map (bytes):
//   iw1t @0  wq/wk/wvf @98304..  iw2t @163840  ow1t @294912  ow2t @4227072
//   flat @13139968 (39.3MB, dead after inner_ml)
//   seq  @52461568  owqt/owkt/owvt @60325888..60424192 (dead after outer_attn)
//   ctxo @13139968 (reuse; dead after fc1 main)
//   part2 @13139968 (reuse; fc2 partials f32 [4][1024][1080], 17.7MB)
//   part1 @37257216 (fc1 partials f16 [3][4096][1024], 25.2MB; clobbers seq/owqt - dead)
//   hout @62423040 ([1024][4096] f16, 8.4MB)  peak 70.8MB < 74.7MB proven

typedef _Float16 f16x8 __attribute__((ext_vector_type(8)));
typedef _Float16 f16x4 __attribute__((ext_vector_type(4)));
typedef float    f32x4 __attribute__((ext_vector_type(4)));
typedef float    f32x16 __attribute__((ext_vector_type(16)));

union F16x8u { f16x8 v; f16x4 q[2]; };

__device__ inline float tanh_fast(float x) {
    float ax = fabsf(x);
    float e  = __expf(2.0f * ax);
    float r  = 1.0f - 2.0f / (e + 1.0f);
    return copysignf(r, x);
}

__device__ inline f32x16 zero16() {
    f32x16 z;
    #pragma unroll
    for (int i = 0; i < 16; i++) z[i] = 0.f;
    return z;
}

// ---------- merged prep: frags + all transposes in ONE dispatch -------------
__device__ inline void tcast_tile(
    const float* __restrict__ W, _Float16* __restrict__ Wt,
    int tileIdx, int nkx, int K, int N, int Kpad,
    _Float16 (*tile)[65], int t)
{
    const int kx = tileIdx % nkx, ny = tileIdx / nkx;
    const int k0 = kx * 64, n0 = ny * 64;
    for (int i = t; i < 4096; i += 256) {
        const int r = i >> 6, c = i & 63;
        const int k = k0 + r, n = n0 + c;
        float v = (k < K && n < N) ? W[(size_t)k * N + n] : 0.f;
        tile[c][r] = (_Float16)v;
    }
    __syncthreads();
    for (int i = t; i < 4096; i += 256) {
        const int r = i >> 6, c = i & 63;
        Wt[(size_t)(n0 + r) * Kpad + k0 + c] = tile[r][c];
    }
}

__global__ __launch_bounds__(256) void k_prep_all(
    const float* __restrict__ iwq, const float* __restrict__ ibq,
    const float* __restrict__ iwk, const float* __restrict__ ibk,
    const float* __restrict__ iwv, const float* __restrict__ ibv,
    const float* __restrict__ iw1, const float* __restrict__ iw2,
    const float* __restrict__ ow1, const float* __restrict__ ow2,
    const float* __restrict__ owq, const float* __restrict__ owk,
    const float* __restrict__ owv,
    _Float16* __restrict__ wqf, _Float16* __restrict__ wkf,
    _Float16* __restrict__ wvf,
    _Float16* __restrict__ iw1t, _Float16* __restrict__ iw2t,
    _Float16* __restrict__ ow1t, _Float16* __restrict__ ow2t,
    _Float16* __restrict__ owqt, _Float16* __restrict__ owkt,
    _Float16* __restrict__ owvt)
{
    __shared__ _Float16 tile[64][65];
    const int b = blockIdx.x, t = threadIdx.x;
    if (b == 0) {
        const float SC = 0.40824829046386307f;   // 1/sqrt(6) folded into Q
        for (int i = t; i < 512; i += 256) {
            const int lanev = i >> 3, jj = i & 7;
            const int n = lanev & 31, grp = lanev >> 5;
            const int h = n >> 3, dk = n & 7;
            float q = 0.f, k = 0.f, v = 0.f;
            if (!grp) {
                if (jj < 3) {
                    if (dk < 6) { q = iwq[h*18 + jj*6 + dk] * SC; k = iwk[h*18 + jj*6 + dk]; }
                    v = iwv[h*24 + jj*8 + dk];
                } else if (jj == 3) {
                    if (dk < 6) { q = ibq[h*6 + dk] * SC; k = ibk[h*6 + dk]; }
                    v = ibv[h*8 + dk];
                }
            }
            wqf[i] = (_Float16)q; wkf[i] = (_Float16)k; wvf[i] = (_Float16)v;
        }
    } else if (b < 161) {
        const int idx = (b - 1) * 256 + t;        // 40960 = 256n x 160k'
        if (idx < 40960) {
            const int n = idx / 160, kp = idx - n * 160;
            const int dv = kp / 20, p = kp - dv * 20;
            float v = (p < 17) ? iw1[(p*8 + dv) * 256 + n] : 0.f;
            iw1t[n * 160 + kp] = (_Float16)v;
        }
    } else if (b < 177) {
        tcast_tile(iw2, iw2t, b - 161, 16, 1024, 64, 1024, tile, t);
    } else if (b < 657) {
        tcast_tile(ow1, ow1t, b - 177, 30, 1920, 1024, 1920, tile, t);
    } else if (b < 1745) {
        tcast_tile(ow2, ow2t, b - 657, 64, 4096, 1080, 4096, tile, t);
    } else {
        const int s = b - 1745;                    // 192 = 3 mats x 4 h x 16
        const int mat = s >> 6, rem = s & 63;
        const int h = rem >> 4, blk = rem & 15;
        const int idx = blk * 256 + t;
        const int n = idx >> 6, k = idx & 63;
        const float* W = (mat == 0) ? owq : (mat == 1) ? owk : owv;
        _Float16* Wt   = (mat == 0) ? owqt : (mat == 1) ? owkt : owvt;
        Wt[h * 4096 + n * 64 + k] = (_Float16)W[h * 4096 + k * 64 + n];
    }
}

// ---------- K1: inner attention, MFMA, 1 wave per (b,s) ---------------------
__global__ __launch_bounds__(256, 3) void k_inner_attn_mfma(
    const float* __restrict__ x,
    const _Float16* __restrict__ wqf, const _Float16* __restrict__ wkf,
    const _Float16* __restrict__ wvf,
    _Float16* __restrict__ flat)
{
    __shared__ __align__(16) _Float16 lds[4][5248];
    const int t = threadIdx.x, lane = t & 63, w = t >> 6;
    const int l31 = lane & 31, grp = lane >> 5;
    const int bs = blockIdx.x * 4 + w;
    _Float16* kq  = &lds[w][0];
    _Float16* qq  = &lds[w][1152];
    _Float16* vt  = &lds[w][2304];
    _Float16* pf  = &lds[w][3456];
    _Float16* fo2 = &lds[w][4608];

    f16x8 xf;
    #pragma unroll
    for (int i = 0; i < 8; i++) xf[i] = (_Float16)0.f;
    if (grp == 0 && l31 < 17) {
        const float* xr = x + (size_t)bs * 51 + l31 * 3;
        xf[0] = (_Float16)xr[0];
        xf[1] = (_Float16)xr[1];
        xf[2] = (_Float16)xr[2];
        xf[3] = (_Float16)1.0f;
    }
    const f16x8 wq8 = *(const f16x8*)&wqf[lane * 8];
    const f16x8 wk8 = *(const f16x8*)&wkf[lane * 8];
    const f16x8 wv8 = *(const f16x8*)&wvf[lane * 8];

    f32x16 kt = __builtin_amdgcn_mfma_f32_32x32x16_f16(wk8, xf, zero16(), 0, 0, 0);
    f32x16 qt = __builtin_amdgcn_mfma_f32_32x32x16_f16(wq8, xf, zero16(), 0, 0, 0);
    f32x16 vv = __builtin_amdgcn_mfma_f32_32x32x16_f16(xf, wv8, zero16(), 0, 0, 0);

    #pragma unroll
    for (int qd = 0; qd < 4; qd++) {
        const int base = 8 * qd + 4 * grp;
        f16x4 a, b, c;
        #pragma unroll
        for (int i = 0; i < 4; i++) {
            a[i] = (_Float16)kt[4*qd + i];
            b[i] = (_Float16)qt[4*qd + i];
            c[i] = (_Float16)vv[4*qd + i];
        }
        *(f16x4*)&kq[l31 * 36 + base] = a;   // kq[j][n]
        *(f16x4*)&qq[l31 * 36 + base] = b;   // qq[p][n]
        *(f16x4*)&vt[l31 * 36 + base] = c;   // vt[n][j]
    }

    #pragma unroll
    for (int h = 0; h < 4; h++) {
        F16x8u ka, qb;
        #pragma unroll
        for (int i = 0; i < 8; i++) { ka.v[i] = (_Float16)0.f; qb.v[i] = (_Float16)0.f; }
        if (grp == 0) {
            ka.q[0] = *(const f16x4*)&kq[l31 * 36 + h * 8];
            ka.q[1] = *(const f16x4*)&kq[l31 * 36 + h * 8 + 4];
            qb.q[0] = *(const f16x4*)&qq[l31 * 36 + h * 8];
            qb.q[1] = *(const f16x4*)&qq[l31 * 36 + h * 8 + 4];
        }
        f32x16 s = __builtin_amdgcn_mfma_f32_32x32x16_f16(ka.v, qb.v, zero16(), 0, 0, 0);

        float mx = -1e30f;
        #pragma unroll
        for (int r = 0; r < 16; r++) {
            const bool val = (r < 8) || (r == 8 && grp == 0);
            if (val) mx = fmaxf(mx, s[r]);
        }
        mx = fmaxf(mx, __shfl_xor(mx, 32));
        float e[16], sum = 0.f;
        #pragma unroll
        for (int r = 0; r < 16; r++) {
            const bool val = (r < 8) || (r == 8 && grp == 0);
            e[r] = val ? __expf(s[r] - mx) : 0.f;
            sum += e[r];
        }
        sum += __shfl_xor(sum, 32);
        const float inv = __builtin_amdgcn_rcpf(sum);
        #pragma unroll
        for (int qd = 0; qd < 4; qd++) {
            f16x4 pk;
            #pragma unroll
            for (int i = 0; i < 4; i++) pk[i] = (_Float16)(e[4*qd + i] * inv);
            *(f16x4*)&pf[l31 * 36 + 8 * qd + 4 * grp] = pk;   // pf[p][j]
        }

        F16x8u pa1, pa2, vb1, vb2;
        pa1.q[0] = *(const f16x4*)&pf[l31 * 36 + grp * 8];
        pa1.q[1] = *(const f16x4*)&pf[l31 * 36 + grp * 8 + 4];
        pa2.q[0] = *(const f16x4*)&pf[l31 * 36 + 16 + grp * 8];
        pa2.q[1] = *(const f16x4*)&pf[l31 * 36 + 16 + grp * 8 + 4];
        const int vr = (h * 8 + (l31 & 7)) * 36;
        vb1.q[0] = *(const f16x4*)&vt[vr + grp * 8];
        vb1.q[1] = *(const f16x4*)&vt[vr + grp * 8 + 4];
        vb2.q[0] = *(const f16x4*)&vt[vr + 16 + grp * 8];
        vb2.q[1] = *(const f16x4*)&vt[vr + 16 + grp * 8 + 4];
        f32x16 c = __builtin_amdgcn_mfma_f32_32x32x16_f16(pa1.v, vb1.v, zero16(), 0, 0, 0);
        c = __builtin_amdgcn_mfma_f32_32x32x16_f16(pa2.v, vb2.v, c, 0, 0, 0);

        if (l31 < 8) {
            #pragma unroll
            for (int qd = 0; qd < 4; qd++) {
                const int jb = 8 * qd + 4 * grp;
                if (jb < 20) {
                    f16x4 ck;
                    #pragma unroll
                    for (int i = 0; i < 4; i++) ck[i] = (_Float16)c[4*qd + i];
                    *(f16x4*)&fo2[h * 160 + l31 * 20 + jb] = ck;
                }
            }
        }
    }

    _Float16* fg = flat + (size_t)bs * 640;
    *(f16x8*)&fg[lane * 8] = *(const f16x8*)&fo2[lane * 8];
    if (lane < 16)
        *(f16x8*)&fg[512 + lane * 8] = *(const f16x8*)&fo2[512 + lane * 8];
}

// ---------- G12: inner ML fused (fc1+tanh -> LDS -> fc2), MFMA --------------
__global__ __launch_bounds__(256) void k_inner_ml_mfma(
    const _Float16* __restrict__ flat,   // [122880][160] (k'=dv*20+p)
    const _Float16* __restrict__ iw1t,   // [256][160]
    const _Float16* __restrict__ iw2t,   // [64][1024]
    const float* __restrict__ ib1, const float* __restrict__ ib2,
    float* __restrict__ seq)             // [30720][64]
{
    __shared__ __align__(16) _Float16 h1l[32][1032];
    float* red = (float*)&h1l[0][0];
    const int t = threadIdx.x, lane = t & 63, w = t >> 6;
    const int q = lane >> 4, ml = lane & 15;
    const int m0  = blockIdx.x * 128;
    const int bs0 = blockIdx.x * 32;

    for (int p = 0; p < 2; p++) {
        f32x4 acc[4][4];
        #pragma unroll
        for (int mi = 0; mi < 4; mi++)
            #pragma unroll
            for (int ni = 0; ni < 4; ni++) acc[mi][ni] = (f32x4){0.f,0.f,0.f,0.f};
        for (int ks = 0; ks < 5; ks++) {
            const int k = ks * 32 + q * 8;
            f16x8 a[4], b[4];
            #pragma unroll
            for (int mi = 0; mi < 4; mi++)
                a[mi] = *(const f16x8*)&flat[(size_t)(m0 + p*64 + mi*16 + ml) * 160 + k];
            #pragma unroll
            for (int ni = 0; ni < 4; ni++)
                b[ni] = *(const f16x8*)&iw1t[(size_t)(w*64 + ni*16 + ml) * 160 + k];
            #pragma unroll
            for (int mi = 0; mi < 4; mi++)
                #pragma unroll
                for (int ni = 0; ni < 4; ni++)
                    acc[mi][ni] = __builtin_amdgcn_mfma_f32_16x16x32_f16(a[mi], b[ni], acc[mi][ni], 0, 0, 0);
        }
        #pragma unroll
        for (int mi = 0; mi < 4; mi++)
            #pragma unroll
            for (int ni = 0; ni < 4; ni++)
                #pragma unroll
                for (int r = 0; r < 4; r++) {
                    const int row = p*64 + mi*16 + q*4 + r;
                    const int col = w*64 + ni*16 + ml;
                    const int bs_l = row >> 2, h = row & 3;
                    h1l[bs_l][h*256 + col] = (_Float16)tanh_fast(acc[mi][ni][r] + ib1[col]);
                }
    }
    __syncthreads();

    f32x4 a2[2][4];
    #pragma unroll
    for (int mi = 0; mi < 2; mi++)
        #pragma unroll
        for (int ni = 0; ni < 4; ni++) a2[mi][ni] = (f32x4){0.f,0.f,0.f,0.f};
    for (int ks = 0; ks < 8; ks++) {
        const int k = w * 256 + ks * 32 + q * 8;
        f16x8 a[2], b[4];
        #pragma unroll
        for (int mi = 0; mi < 2; mi++)
            a[mi] = *(const f16x8*)&h1l[mi*16 + ml][k];
        #pragma unroll
        for (int ni = 0; ni < 4; ni++)
            b[ni] = *(const f16x8*)&iw2t[(size_t)(ni*16 + ml) * 1024 + k];
        #pragma unroll
        for (int mi = 0; mi < 2; mi++)
            #pragma unroll
            for (int ni = 0; ni < 4; ni++)
                a2[mi][ni] = __builtin_amdgcn_mfma_f32_16x16x32_f16(a[mi], b[ni], a2[mi][ni], 0, 0, 0);
    }
    __syncthreads();
    #pragma unroll
    for (int mi = 0; mi < 2; mi++)
        #pragma unroll
        for (int ni = 0; ni < 4; ni++)
            #pragma unroll
            for (int r = 0; r < 4; r++) {
                const int row = mi*16 + q*4 + r;
                const int col = ni*16 + ml;
                red[(size_t)w*2048 + row*64 + col] = a2[mi][ni][r];
            }
    __syncthreads();
    for (int i = t; i < 2048; i += 256) {
        const int row = i >> 6, col = i & 63;
        float s = red[i] + red[2048 + i] + red[4096 + i] + red[6144 + i] + ib2[col];
        seq[(size_t)(bs0 + row) * 64 + col] = s;
    }
}

// ---------- K3: outer attention, MFMA, 1 block/b, 1 wave/head ---------------
__device__ inline void oa_proj_rows(
    const _Float16 (*seqf)[72], const _Float16* __restrict__ wt,
    const float* __restrict__ bias, _Float16 (*dst)[72], int q, int ml)
{
    f32x4 acc[2][4];
    #pragma unroll
    for (int mi = 0; mi < 2; mi++)
        #pragma unroll
        for (int ni = 0; ni < 4; ni++) acc[mi][ni] = (f32x4){0.f,0.f,0.f,0.f};
    #pragma unroll
    for (int k0 = 0; k0 < 64; k0 += 32) {
        f16x8 a[2], bb[4];
        #pragma unroll
        for (int mi = 0; mi < 2; mi++) a[mi] = *(const f16x8*)&seqf[mi*16 + ml][k0 + q*8];
        #pragma unroll
        for (int ni = 0; ni < 4; ni++) bb[ni] = *(const f16x8*)&wt[(size_t)(ni*16 + ml)*64 + k0 + q*8];
        #pragma unroll
        for (int mi = 0; mi < 2; mi++)
            #pragma unroll
            for (int ni = 0; ni < 4; ni++)
                acc[mi][ni] = __builtin_amdgcn_mfma_f32_16x16x32_f16(a[mi], bb[ni], acc[mi][ni], 0, 0, 0);
    }
    #pragma unroll
    for (int ni = 0; ni < 4; ni++) {
        const float bi = bias[ni*16 + ml];
        #pragma unroll
        for (int mi = 0; mi < 2; mi++)
            #pragma unroll
            for (int r = 0; r < 4; r++)
                dst[mi*16 + q*4 + r][ni*16 + ml] = (_Float16)(acc[mi][ni][r] + bi);
    }
}

__device__ inline void oa_proj_t(
    const _Float16 (*seqf)[72], const _Float16* __restrict__ wt,
    const float* __restrict__ bias, _Float16 (*dstT)[40], int q, int ml)
{
    f32x4 acc[2][4];
    #pragma unroll
    for (int mi = 0; mi < 2; mi++)
        #pragma unroll
        for (int ni = 0; ni < 4; ni++) acc[mi][ni] = (f32x4){0.f,0.f,0.f,0.f};
    #pragma unroll
    for (int k0 = 0; k0 < 64; k0 += 32) {
        f16x8 a[2], bb[4];
        #pragma unroll
        for (int mi = 0; mi < 2; mi++) a[mi] = *(const f16x8*)&seqf[mi*16 + ml][k0 + q*8];
        #pragma unroll
        for (int ni = 0; ni < 4; ni++) bb[ni] = *(const f16x8*)&wt[(size_t)(ni*16 + ml)*64 + k0 + q*8];
        #pragma unroll
        for (int mi = 0; mi < 2; mi++)
            #pragma unroll
            for (int ni = 0; ni < 4; ni++)
                acc[mi][ni] = __builtin_amdgcn_mfma_f32_16x16x32_f16(a[mi], bb[ni], acc[mi][ni], 0, 0, 0);
    }
    #pragma unroll
    for (int ni = 0; ni < 4; ni++) {
        const float bi = bias[ni*16 + ml];
        #pragma unroll
        for (int mi = 0; mi < 2; mi++)
            #pragma unroll
            for (int r = 0; r < 4; r++)
                dstT[ni*16 + ml][mi*16 + q*4 + r] = (_Float16)(acc[mi][ni][r] + bi);
    }
}

__global__ __launch_bounds__(256) void k_outer_attn_mfma(
    const float* __restrict__ seq,
    const _Float16* __restrict__ owqt,
    const _Float16* __restrict__ owkt,
    const _Float16* __restrict__ owvt,
    const float* __restrict__ obq, const float* __restrict__ obk,
    const float* __restrict__ obv,
    _Float16* __restrict__ ctxo)
{
    __shared__ __align__(16) _Float16 seqf[32][72];
    __shared__ __align__(16) _Float16 qf[4][32][72];
    __shared__ __align__(16) _Float16 kf[4][32][72];
    __shared__ __align__(16) _Float16 vt[4][64][40];
    __shared__ __align__(16) _Float16 pf[4][32][40];
    const int t = threadIdx.x, lane = t & 63, w = t >> 6;
    const int q = lane >> 4, ml = lane & 15;
    const int b = blockIdx.x;

    const float* sb = seq + (size_t)b * 1920;
    for (int i = t; i < 2048; i += 256) {
        const int row = i >> 6, col = i & 63;
        seqf[row][col] = (_Float16)(row < 30 ? sb[row*64 + col] : 0.0f);
    }
    __syncthreads();

    oa_proj_rows(seqf, owqt + w*4096, obq + w*64, qf[w], q, ml);
    oa_proj_rows(seqf, owkt + w*4096, obk + w*64, kf[w], q, ml);
    oa_proj_t   (seqf, owvt + w*4096, obv + w*64, vt[w], q, ml);
    __syncthreads();

    f32x4 sc[2][2];
    #pragma unroll
    for (int mi = 0; mi < 2; mi++)
        #pragma unroll
        for (int ni = 0; ni < 2; ni++) sc[mi][ni] = (f32x4){0.f,0.f,0.f,0.f};
    #pragma unroll
    for (int k0 = 0; k0 < 64; k0 += 32) {
        f16x8 aq[2], bk[2];
        #pragma unroll
        for (int mi = 0; mi < 2; mi++) aq[mi] = *(const f16x8*)&qf[w][mi*16 + ml][k0 + q*8];
        #pragma unroll
        for (int ni = 0; ni < 2; ni++) bk[ni] = *(const f16x8*)&kf[w][ni*16 + ml][k0 + q*8];
        #pragma unroll
        for (int mi = 0; mi < 2; mi++)
            #pragma unroll
            for (int ni = 0; ni < 2; ni++)
                sc[mi][ni] = __builtin_amdgcn_mfma_f32_16x16x32_f16(aq[mi], bk[ni], sc[mi][ni], 0, 0, 0);
    }

    const bool maskhi = (ml >= 14);
    #pragma unroll
    for (int mi = 0; mi < 2; mi++) {
        #pragma unroll
        for (int r = 0; r < 4; r++) {
            const float s0 = sc[mi][0][r] * 0.125f;
            const float s1 = maskhi ? -1e30f : sc[mi][1][r] * 0.125f;
            float mx = fmaxf(s0, s1);
            #pragma unroll
            for (int off = 1; off < 16; off <<= 1) mx = fmaxf(mx, __shfl_xor(mx, off, 64));
            const float e0 = __expf(s0 - mx);
            const float e1 = __expf(s1 - mx);
            float sm = e0 + e1;
            #pragma unroll
            for (int off = 1; off < 16; off <<= 1) sm += __shfl_xor(sm, off, 64);
            const float inv = 1.0f / sm;
            pf[w][mi*16 + q*4 + r][ml]      = (_Float16)(e0 * inv);
            pf[w][mi*16 + q*4 + r][16 + ml] = (_Float16)(e1 * inv);
        }
    }
    __syncthreads();

    f16x8 ap[2], bv[4];
    #pragma unroll
    for (int mi = 0; mi < 2; mi++) ap[mi] = *(const f16x8*)&pf[w][mi*16 + ml][q*8];
    #pragma unroll
    for (int ni = 0; ni < 4; ni++) bv[ni] = *(const f16x8*)&vt[w][ni*16 + ml][q*8];
    f32x4 oa[2][4];
    #pragma unroll
    for (int mi = 0; mi < 2; mi++)
        #pragma unroll
        for (int ni = 0; ni < 4; ni++) {
            oa[mi][ni] = (f32x4){0.f,0.f,0.f,0.f};
            oa[mi][ni] = __builtin_amdgcn_mfma_f32_16x16x32_f16(ap[mi], bv[ni], oa[mi][ni], 0, 0, 0);
        }

    _Float16* co = ctxo + (size_t)(b*4 + w) * 1920;
    #pragma unroll
    for (int mi = 0; mi < 2; mi++)
        #pragma unroll
        for (int r = 0; r < 4; r++) {
            const int row = mi*16 + q*4 + r;
            if (row < 30) {
                #pragma unroll
                for (int ni = 0; ni < 4; ni++)
                    co[row*64 + ni*16 + ml] = (_Float16)oa[mi][ni][r];
            }
        }
}

// ---------- G3a: outer fc1 main, block-level K-split-3 ----------------------
// 6144 blocks x 4 waves; tile 32x64; kc in [0,3) block-K=640, wave-K=160
// (5 iters); depth-2 prefetch; partials f16 -> part1[kc][4096][1024]
__global__ __launch_bounds__(256) void k_outer_fc1_mfma(
    const _Float16* __restrict__ ctxo,   // [4096][1920]
    const _Float16* __restrict__ ow1t,   // [1024][1920]
    _Float16* __restrict__ part1)        // [3][4096][1024]
{
    __shared__ float red[4][32][65];     // 33.3 KB
    const int t = threadIdx.x, lane = t & 63, w = t >> 6;
    const int q = lane >> 4, ml = lane & 15;
    const int bid = blockIdx.x;
    const int kc = bid % 3;
    const int rest = bid / 3;
    const int M0 = (rest >> 4) * 32;     // 128 M-tiles
    const int N0 = (rest & 15) * 64;     // 16 N-tiles
    const int kk0 = kc * 640 + w * 160 + q * 8;
    f32x4 acc[2][4];
    #pragma unroll
    for (int mi = 0; mi < 2; mi++)
        #pragma unroll
        for (int ni = 0; ni < 4; ni++) acc[mi][ni] = (f32x4){0.f,0.f,0.f,0.f};
    f16x8 a[2][2], b[2][4];
    #pragma unroll
    for (int mi = 0; mi < 2; mi++)
        a[0][mi] = *(const f16x8*)&ctxo[(size_t)(M0 + mi*16 + ml) * 1920 + kk0];
    #pragma unroll
    for (int ni = 0; ni < 4; ni++)
        b[0][ni] = *(const f16x8*)&ow1t[(size_t)(N0 + ni*16 + ml) * 1920 + kk0];
    #pragma unroll
    for (int ks = 0; ks < 5; ks++) {
        const int cur = ks & 1, nxt = cur ^ 1;
        if (ks < 4) {
            const int kn = kk0 + (ks + 1) * 32;
            #pragma unroll
            for (int mi = 0; mi < 2; mi++)
                a[nxt][mi] = *(const f16x8*)&ctxo[(size_t)(M0 + mi*16 + ml) * 1920 + kn];
            #pragma unroll
            for (int ni = 0; ni < 4; ni++)
                b[nxt][ni] = *(const f16x8*)&ow1t[(size_t)(N0 + ni*16 + ml) * 1920 + kn];
        }
        #pragma unroll
        for (int mi = 0; mi < 2; mi++)
            #pragma unroll
            for (int ni = 0; ni < 4; ni++)
                acc[mi][ni] = __builtin_amdgcn_mfma_f32_16x16x32_f16(a[cur][mi], b[cur][ni], acc[mi][ni], 0, 0, 0);
    }
    #pragma unroll
    for (int mi = 0; mi < 2; mi++)
        #pragma unroll
        for (int ni = 0; ni < 4; ni++)
            #pragma unroll
            for (int r = 0; r < 4; r++)
                red[w][mi*16 + q*4 + r][ni*16 + ml] = acc[mi][ni][r];
    __syncthreads();
    for (int i = t; i < 2048; i += 256) {
        const int row = i >> 6, col = i & 63;
        const float s = red[0][row][col] + red[1][row][col] + red[2][row][col] + red[3][row][col];
        part1[(size_t)kc * 4194304 + (size_t)(M0 + row) * 1024 + N0 + col] = (_Float16)s;
    }
}

// ---------- G3b: fc1 reduce + bias + tanh -> hout f16 -----------------------
// 2048 blocks x 256 thr; 8 elems/thread (f16x8 vectorized)
__global__ __launch_bounds__(256) void k_fc1_reduce(
    const _Float16* __restrict__ part1, const float* __restrict__ ob1,
    _Float16* __restrict__ hout)         // [4096][1024]
{
    const int i8 = (blockIdx.x * 256 + threadIdx.x) * 8;   // < 4194304
    const int col = i8 & 1023;
    const f16x8 p0 = *(const f16x8*)&part1[i8];
    const f16x8 p1 = *(const f16x8*)&part1[4194304 + i8];
    const f16x8 p2 = *(const f16x8*)&part1[8388608 + i8];
    f16x8 o;
    #pragma unroll
    for (int j = 0; j < 8; j++) {
        const float s = (float)p0[j] + (float)p1[j] + (float)p2[j] + ob1[col + j];
        o[j] = (_Float16)tanh_fast(s);
    }
    *(f16x8*)&hout[i8] = o;
}

// ---------- G4a: outer fc2 main, block-level K-split-4 ----------------------
// 2176 blocks x 4 waves; tile 32x64; block kc in [0,4); wave K=256; prefetch
__global__ __launch_bounds__(256) void k_outer_fc2_mfma(
    const _Float16* __restrict__ hout,   // [1024][4096]
    const _Float16* __restrict__ ow2t,   // [1088][4096]
    float* __restrict__ part)            // [4][1024][1080]
{
    __shared__ float red[4][32][65];
    const int t = threadIdx.x, lane = t & 63, w = t >> 6;
    const int q = lane >> 4, ml = lane & 15;
    const int bid = blockIdx.x;
    const int kc = bid & 3;
    const int rest = bid >> 2;
    const int M0 = (rest / 17) * 32;
    const int N0 = (rest % 17) * 64;
    const int kk0 = kc * 1024 + w * 256 + q * 8;
    f32x4 acc[2][4];
    #pragma unroll
    for (int mi = 0; mi < 2; mi++)
        #pragma unroll
        for (int ni = 0; ni < 4; ni++) acc[mi][ni] = (f32x4){0.f,0.f,0.f,0.f};
    f16x8 a[2][2], b[2][4];
    #pragma unroll
    for (int mi = 0; mi < 2; mi++)
        a[0][mi] = *(const f16x8*)&hout[(size_t)(M0 + mi*16 + ml) * 4096 + kk0];
    #pragma unroll
    for (int ni = 0; ni < 4; ni++)
        b[0][ni] = *(const f16x8*)&ow2t[(size_t)(N0 + ni*16 + ml) * 4096 + kk0];
    #pragma unroll
    for (int ks = 0; ks < 8; ks++) {
        const int cur = ks & 1, nxt = cur ^ 1;
        if (ks < 7) {
            const int kn = kk0 + (ks + 1) * 32;
            #pragma unroll
            for (int mi = 0; mi < 2; mi++)
                a[nxt][mi] = *(const f16x8*)&hout[(size_t)(M0 + mi*16 + ml) * 4096 + kn];
            #pragma unroll
            for (int ni = 0; ni < 4; ni++)
                b[nxt][ni] = *(const f16x8*)&ow2t[(size_t)(N0 + ni*16 + ml) * 4096 + kn];
        }
        #pragma unroll
        for (int mi = 0; mi < 2; mi++)
            #pragma unroll
            for (int ni = 0; ni < 4; ni++)
                acc[mi][ni] = __builtin_amdgcn_mfma_f32_16x16x32_f16(a[cur][mi], b[cur][ni], acc[mi][ni], 0, 0, 0);
    }
    #pragma unroll
    for (int mi = 0; mi < 2; mi++)
        #pragma unroll
        for (int ni = 0; ni < 4; ni++)
            #pragma unroll
            for (int r = 0; r < 4; r++)
                red[w][mi*16 + q*4 + r][ni*16 + ml] = acc[mi][ni][r];
    __syncthreads();
    for (int i = t; i < 2048; i += 256) {
        const int row = i >> 6, col = i & 63;
        const int n = N0 + col;
        if (n < 1080) {
            const float s = red[0][row][col] + red[1][row][col] + red[2][row][col] + red[3][row][col];
            part[(size_t)kc * 1105920 + (size_t)(M0 + row) * 1080 + n] = s;
        }
    }
}

// ---------- G4b: fc2 reduce + bias ------------------------------------------
__global__ __launch_bounds__(256) void k_fc2_reduce(
    const float* __restrict__ part, const float* __restrict__ ob2,
    float* __restrict__ out)
{
    const int idx = blockIdx.x * 256 + threadIdx.x;
    if (idx >= 1105920) return;
    const int n = idx % 1080;
    out[idx] = part[idx] + part[1105920 + idx] + part[2211840 + idx]
             + part[3317760 + idx] + ob2[n];
}

extern "C" void kernel_launch(void* const* d_in, const int* in_sizes, int n_in,
                              void* d_out, int out_size, void* d_ws, size_t ws_size,
                              hipStream_t stream) {
    const float* x   = (const float*)d_in[0];
    const float* iwq = (const float*)d_in[1];
    const float* ibq = (const float*)d_in[2];
    const float* iwk = (const float*)d_in[3];
    const float* ibk = (const float*)d_in[4];
    const float* iwv = (const float*)d_in[5];
    const float* ibv = (const float*)d_in[6];
    const float* iw1 = (const float*)d_in[7];
    const float* ib1 = (const float*)d_in[8];
    const float* iw2 = (const float*)d_in[9];
    const float* ib2 = (const float*)d_in[10];
    const float* owq = (const float*)d_in[11];
    const float* obq = (const float*)d_in[12];
    const float* owk = (const float*)d_in[13];
    const float* obk = (const float*)d_in[14];
    const float* owv = (const float*)d_in[15];
    const float* obv = (const float*)d_in[16];
    const float* ow1 = (const float*)d_in[17];
    const float* ob1 = (const float*)d_in[18];
    const float* ow2 = (const float*)d_in[19];
    const float* ob2 = (const float*)d_in[20];

    char* ws = (char*)d_ws;
    _Float16* iw1t   = (_Float16*)(ws + 0);          // [256][160]
    _Float16* wqf    = (_Float16*)(ws + 98304);      // [64][8]
    _Float16* wkf    = (_Float16*)(ws + 99328);
    _Float16* wvf    = (_Float16*)(ws + 100352);
    _Float16* iw2t   = (_Float16*)(ws + 163840);     // [64][1024]
    _Float16* ow1t   = (_Float16*)(ws + 294912);     // [1024][1920]
    _Float16* ow2t   = (_Float16*)(ws + 4227072);    // [1088][4096]
    _Float16* flat   = (_Float16*)(ws + 13139968);   // [122880][160]
    float*    seq    = (float*)   (ws + 52461568);   // [30720][64]
    _Float16* owqt   = (_Float16*)(ws + 60325888);   // [4][64][64]
    _Float16* owkt   = (_Float16*)(ws + 60358656);
    _Float16* owvt   = (_Float16*)(ws + 60391424);
    _Float16* ctxo   = (_Float16*)(ws + 13139968);   // reuse (dead flat)
    float*    part2  = (float*)   (ws + 13139968);   // fc2 partials (dead ctxo), 17.7MB
    _Float16* part1  = (_Float16*)(ws + 37257216);   // fc1 partials f16, 25.2MB (dead seq/owqt)
    _Float16* houtb  = (_Float16*)(ws + 62423040);   // [1024][4096] f16, ends 70.8MB
    float*    out    = (float*)d_out;

    k_prep_all       <<<dim3(1937), dim3(256), 0, stream>>>(
        iwq, ibq, iwk, ibk, iwv, ibv, iw1, iw2, ow1, ow2, owq, owk, owv,
        wqf, wkf, wvf, iw1t, iw2t, ow1t, ow2t, owqt, owkt, owvt);
    k_inner_attn_mfma<<<dim3(7680), dim3(256), 0, stream>>>(x, wqf, wkf, wvf, flat);
    k_inner_ml_mfma  <<<dim3(960),  dim3(256), 0, stream>>>(flat, iw1t, iw2t, ib1, ib2, seq);
    k_outer_attn_mfma<<<dim3(1024), dim3(256), 0, stream>>>(seq, owqt, owkt, owvt, obq, obk, obv, ctxo);
    k_outer_fc1_mfma <<<dim3(6144), dim3(256), 0, stream>>>(ctxo, ow1t, part1);
    k_fc1_reduce     <<<dim3(2048), dim3(256), 0, stream>>>(part1, ob1, houtb);
    k_outer_fc2_mfma <<<dim3(2176), dim3(256), 0, stream>>>(houtb, ow2t, part2);
    k_fc2_reduce     <<<dim3(4320), dim3(256), 0, stream>>>(part2, ob2, out);
}

// Round 12
// 338.135 us; speedup vs baseline: 1.0976x; 1.0976x over previous
//
#include <hip/hip_runtime.h>

// DoubleAttention: B=1024, S_OUT=30, S_IN=17, D_IN=3, H=4
// Round 12: fc1 consolidated to best-known per-wave stream (R8: 64x64/wave,
// K=960, 30 iters) repackaged as 128x64 blocks x 4 waves (2 M-half x 2 K-half),
// grid 512 -> same 8 waves/CU, halved B L2-demand, direct tanh epilogue
// (fc1 reduce kernel deleted). Evidence: R9-R11 showed shorter K-loops and
// more waves regress; compiler elides source prefetch regardless (VGPR 44-88).
//
// ws map (bytes) [R8 layout restored]:
//   iw1t @0  wq/wk/wvf @98304..  iw2t @163840  ow1t @294912  ow2t @4227072
//   flat @13139968 (39.3MB, dead after inner_ml)
//   seq  @52461568  owqt/owkt/owvt @60325888..60424192
//   ctxo @13139968 (reuse; dead after fc1)
//   part2 @13139968 (reuse; fc2 partials f32 [4][1024][1080], 17.7MB)
//   hout @40000000 ([1024][4096] f16, 8.4MB; inside dead flat region)

typedef _Float16 f16x8 __attribute__((ext_vector_type(8)));
typedef _Float16 f16x4 __attribute__((ext_vector_type(4)));
typedef float    f32x4 __attribute__((ext_vector_type(4)));
typedef float    f32x16 __attribute__((ext_vector_type(16)));

union F16x8u { f16x8 v; f16x4 q[2]; };

__device__ inline float tanh_fast(float x) {
    float ax = fabsf(x);
    float e  = __expf(2.0f * ax);
    float r  = 1.0f - 2.0f / (e + 1.0f);
    return copysignf(r, x);
}

__device__ inline f32x16 zero16() {
    f32x16 z;
    #pragma unroll
    for (int i = 0; i < 16; i++) z[i] = 0.f;
    return z;
}

// ---------- merged prep: frags + all transposes in ONE dispatch -------------
__device__ inline void tcast_tile(
    const float* __restrict__ W, _Float16* __restrict__ Wt,
    int tileIdx, int nkx, int K, int N, int Kpad,
    _Float16 (*tile)[65], int t)
{
    const int kx = tileIdx % nkx, ny = tileIdx / nkx;
    const int k0 = kx * 64, n0 = ny * 64;
    for (int i = t; i < 4096; i += 256) {
        const int r = i >> 6, c = i & 63;
        const int k = k0 + r, n = n0 + c;
        float v = (k < K && n < N) ? W[(size_t)k * N + n] : 0.f;
        tile[c][r] = (_Float16)v;
    }
    __syncthreads();
    for (int i = t; i < 4096; i += 256) {
        const int r = i >> 6, c = i & 63;
        Wt[(size_t)(n0 + r) * Kpad + k0 + c] = tile[r][c];
    }
}

__global__ __launch_bounds__(256) void k_prep_all(
    const float* __restrict__ iwq, const float* __restrict__ ibq,
    const float* __restrict__ iwk, const float* __restrict__ ibk,
    const float* __restrict__ iwv, const float* __restrict__ ibv,
    const float* __restrict__ iw1, const float* __restrict__ iw2,
    const float* __restrict__ ow1, const float* __restrict__ ow2,
    const float* __restrict__ owq, const float* __restrict__ owk,
    const float* __restrict__ owv,
    _Float16* __restrict__ wqf, _Float16* __restrict__ wkf,
    _Float16* __restrict__ wvf,
    _Float16* __restrict__ iw1t, _Float16* __restrict__ iw2t,
    _Float16* __restrict__ ow1t, _Float16* __restrict__ ow2t,
    _Float16* __restrict__ owqt, _Float16* __restrict__ owkt,
    _Float16* __restrict__ owvt)
{
    __shared__ _Float16 tile[64][65];
    const int b = blockIdx.x, t = threadIdx.x;
    if (b == 0) {
        const float SC = 0.40824829046386307f;   // 1/sqrt(6) folded into Q
        for (int i = t; i < 512; i += 256) {
            const int lanev = i >> 3, jj = i & 7;
            const int n = lanev & 31, grp = lanev >> 5;
            const int h = n >> 3, dk = n & 7;
            float q = 0.f, k = 0.f, v = 0.f;
            if (!grp) {
                if (jj < 3) {
                    if (dk < 6) { q = iwq[h*18 + jj*6 + dk] * SC; k = iwk[h*18 + jj*6 + dk]; }
                    v = iwv[h*24 + jj*8 + dk];
                } else if (jj == 3) {
                    if (dk < 6) { q = ibq[h*6 + dk] * SC; k = ibk[h*6 + dk]; }
                    v = ibv[h*8 + dk];
                }
            }
            wqf[i] = (_Float16)q; wkf[i] = (_Float16)k; wvf[i] = (_Float16)v;
        }
    } else if (b < 161) {
        const int idx = (b - 1) * 256 + t;        // 40960 = 256n x 160k'
        if (idx < 40960) {
            const int n = idx / 160, kp = idx - n * 160;
            const int dv = kp / 20, p = kp - dv * 20;
            float v = (p < 17) ? iw1[(p*8 + dv) * 256 + n] : 0.f;
            iw1t[n * 160 + kp] = (_Float16)v;
        }
    } else if (b < 177) {
        tcast_tile(iw2, iw2t, b - 161, 16, 1024, 64, 1024, tile, t);
    } else if (b < 657) {
        tcast_tile(ow1, ow1t, b - 177, 30, 1920, 1024, 1920, tile, t);
    } else if (b < 1745) {
        tcast_tile(ow2, ow2t, b - 657, 64, 4096, 1080, 4096, tile, t);
    } else {
        const int s = b - 1745;                    // 192 = 3 mats x 4 h x 16
        const int mat = s >> 6, rem = s & 63;
        const int h = rem >> 4, blk = rem & 15;
        const int idx = blk * 256 + t;
        const int n = idx >> 6, k = idx & 63;
        const float* W = (mat == 0) ? owq : (mat == 1) ? owk : owv;
        _Float16* Wt   = (mat == 0) ? owqt : (mat == 1) ? owkt : owvt;
        Wt[h * 4096 + n * 64 + k] = (_Float16)W[h * 4096 + k * 64 + n];
    }
}

// ---------- K1: inner attention, MFMA, 1 wave per (b,s) ---------------------
__global__ __launch_bounds__(256, 3) void k_inner_attn_mfma(
    const float* __restrict__ x,
    const _Float16* __restrict__ wqf, const _Float16* __restrict__ wkf,
    const _Float16* __restrict__ wvf,
    _Float16* __restrict__ flat)
{
    __shared__ __align__(16) _Float16 lds[4][5248];
    const int t = threadIdx.x, lane = t & 63, w = t >> 6;
    const int l31 = lane & 31, grp = lane >> 5;
    const int bs = blockIdx.x * 4 + w;
    _Float16* kq  = &lds[w][0];
    _Float16* qq  = &lds[w][1152];
    _Float16* vt  = &lds[w][2304];
    _Float16* pf  = &lds[w][3456];
    _Float16* fo2 = &lds[w][4608];

    f16x8 xf;
    #pragma unroll
    for (int i = 0; i < 8; i++) xf[i] = (_Float16)0.f;
    if (grp == 0 && l31 < 17) {
        const float* xr = x + (size_t)bs * 51 + l31 * 3;
        xf[0] = (_Float16)xr[0];
        xf[1] = (_Float16)xr[1];
        xf[2] = (_Float16)xr[2];
        xf[3] = (_Float16)1.0f;
    }
    const f16x8 wq8 = *(const f16x8*)&wqf[lane * 8];
    const f16x8 wk8 = *(const f16x8*)&wkf[lane * 8];
    const f16x8 wv8 = *(const f16x8*)&wvf[lane * 8];

    f32x16 kt = __builtin_amdgcn_mfma_f32_32x32x16_f16(wk8, xf, zero16(), 0, 0, 0);
    f32x16 qt = __builtin_amdgcn_mfma_f32_32x32x16_f16(wq8, xf, zero16(), 0, 0, 0);
    f32x16 vv = __builtin_amdgcn_mfma_f32_32x32x16_f16(xf, wv8, zero16(), 0, 0, 0);

    #pragma unroll
    for (int qd = 0; qd < 4; qd++) {
        const int base = 8 * qd + 4 * grp;
        f16x4 a, b, c;
        #pragma unroll
        for (int i = 0; i < 4; i++) {
            a[i] = (_Float16)kt[4*qd + i];
            b[i] = (_Float16)qt[4*qd + i];
            c[i] = (_Float16)vv[4*qd + i];
        }
        *(f16x4*)&kq[l31 * 36 + base] = a;   // kq[j][n]
        *(f16x4*)&qq[l31 * 36 + base] = b;   // qq[p][n]
        *(f16x4*)&vt[l31 * 36 + base] = c;   // vt[n][j]
    }

    #pragma unroll
    for (int h = 0; h < 4; h++) {
        F16x8u ka, qb;
        #pragma unroll
        for (int i = 0; i < 8; i++) { ka.v[i] = (_Float16)0.f; qb.v[i] = (_Float16)0.f; }
        if (grp == 0) {
            ka.q[0] = *(const f16x4*)&kq[l31 * 36 + h * 8];
            ka.q[1] = *(const f16x4*)&kq[l31 * 36 + h * 8 + 4];
            qb.q[0] = *(const f16x4*)&qq[l31 * 36 + h * 8];
            qb.q[1] = *(const f16x4*)&qq[l31 * 36 + h * 8 + 4];
        }
        f32x16 s = __builtin_amdgcn_mfma_f32_32x32x16_f16(ka.v, qb.v, zero16(), 0, 0, 0);

        float mx = -1e30f;
        #pragma unroll
        for (int r = 0; r < 16; r++) {
            const bool val = (r < 8) || (r == 8 && grp == 0);
            if (val) mx = fmaxf(mx, s[r]);
        }
        mx = fmaxf(mx, __shfl_xor(mx, 32));
        float e[16], sum = 0.f;
        #pragma unroll
        for (int r = 0; r < 16; r++) {
            const bool val = (r < 8) || (r == 8 && grp == 0);
            e[r] = val ? __expf(s[r] - mx) : 0.f;
            sum += e[r];
        }
        sum += __shfl_xor(sum, 32);
        const float inv = __builtin_amdgcn_rcpf(sum);
        #pragma unroll
        for (int qd = 0; qd < 4; qd++) {
            f16x4 pk;
            #pragma unroll
            for (int i = 0; i < 4; i++) pk[i] = (_Float16)(e[4*qd + i] * inv);
            *(f16x4*)&pf[l31 * 36 + 8 * qd + 4 * grp] = pk;   // pf[p][j]
        }

        F16x8u pa1, pa2, vb1, vb2;
        pa1.q[0] = *(const f16x4*)&pf[l31 * 36 + grp * 8];
        pa1.q[1] = *(const f16x4*)&pf[l31 * 36 + grp * 8 + 4];
        pa2.q[0] = *(const f16x4*)&pf[l31 * 36 + 16 + grp * 8];
        pa2.q[1] = *(const f16x4*)&pf[l31 * 36 + 16 + grp * 8 + 4];
        const int vr = (h * 8 + (l31 & 7)) * 36;
        vb1.q[0] = *(const f16x4*)&vt[vr + grp * 8];
        vb1.q[1] = *(const f16x4*)&vt[vr + grp * 8 + 4];
        vb2.q[0] = *(const f16x4*)&vt[vr + 16 + grp * 8];
        vb2.q[1] = *(const f16x4*)&vt[vr + 16 + grp * 8 + 4];
        f32x16 c = __builtin_amdgcn_mfma_f32_32x32x16_f16(pa1.v, vb1.v, zero16(), 0, 0, 0);
        c = __builtin_amdgcn_mfma_f32_32x32x16_f16(pa2.v, vb2.v, c, 0, 0, 0);

        if (l31 < 8) {
            #pragma unroll
            for (int qd = 0; qd < 4; qd++) {
                const int jb = 8 * qd + 4 * grp;
                if (jb < 20) {
                    f16x4 ck;
                    #pragma unroll
                    for (int i = 0; i < 4; i++) ck[i] = (_Float16)c[4*qd + i];
                    *(f16x4*)&fo2[h * 160 + l31 * 20 + jb] = ck;
                }
            }
        }
    }

    _Float16* fg = flat + (size_t)bs * 640;
    *(f16x8*)&fg[lane * 8] = *(const f16x8*)&fo2[lane * 8];
    if (lane < 16)
        *(f16x8*)&fg[512 + lane * 8] = *(const f16x8*)&fo2[512 + lane * 8];
}

// ---------- G12: inner ML fused (fc1+tanh -> LDS -> fc2), MFMA --------------
__global__ __launch_bounds__(256) void k_inner_ml_mfma(
    const _Float16* __restrict__ flat,   // [122880][160] (k'=dv*20+p)
    const _Float16* __restrict__ iw1t,   // [256][160]
    const _Float16* __restrict__ iw2t,   // [64][1024]
    const float* __restrict__ ib1, const float* __restrict__ ib2,
    float* __restrict__ seq)             // [30720][64]
{
    __shared__ __align__(16) _Float16 h1l[32][1032];
    float* red = (float*)&h1l[0][0];
    const int t = threadIdx.x, lane = t & 63, w = t >> 6;
    const int q = lane >> 4, ml = lane & 15;
    const int m0  = blockIdx.x * 128;
    const int bs0 = blockIdx.x * 32;

    for (int p = 0; p < 2; p++) {
        f32x4 acc[4][4];
        #pragma unroll
        for (int mi = 0; mi < 4; mi++)
            #pragma unroll
            for (int ni = 0; ni < 4; ni++) acc[mi][ni] = (f32x4){0.f,0.f,0.f,0.f};
        for (int ks = 0; ks < 5; ks++) {
            const int k = ks * 32 + q * 8;
            f16x8 a[4], b[4];
            #pragma unroll
            for (int mi = 0; mi < 4; mi++)
                a[mi] = *(const f16x8*)&flat[(size_t)(m0 + p*64 + mi*16 + ml) * 160 + k];
            #pragma unroll
            for (int ni = 0; ni < 4; ni++)
                b[ni] = *(const f16x8*)&iw1t[(size_t)(w*64 + ni*16 + ml) * 160 + k];
            #pragma unroll
            for (int mi = 0; mi < 4; mi++)
                #pragma unroll
                for (int ni = 0; ni < 4; ni++)
                    acc[mi][ni] = __builtin_amdgcn_mfma_f32_16x16x32_f16(a[mi], b[ni], acc[mi][ni], 0, 0, 0);
        }
        #pragma unroll
        for (int mi = 0; mi < 4; mi++)
            #pragma unroll
            for (int ni = 0; ni < 4; ni++)
                #pragma unroll
                for (int r = 0; r < 4; r++) {
                    const int row = p*64 + mi*16 + q*4 + r;
                    const int col = w*64 + ni*16 + ml;
                    const int bs_l = row >> 2, h = row & 3;
                    h1l[bs_l][h*256 + col] = (_Float16)tanh_fast(acc[mi][ni][r] + ib1[col]);
                }
    }
    __syncthreads();

    f32x4 a2[2][4];
    #pragma unroll
    for (int mi = 0; mi < 2; mi++)
        #pragma unroll
        for (int ni = 0; ni < 4; ni++) a2[mi][ni] = (f32x4){0.f,0.f,0.f,0.f};
    for (int ks = 0; ks < 8; ks++) {
        const int k = w * 256 + ks * 32 + q * 8;
        f16x8 a[2], b[4];
        #pragma unroll
        for (int mi = 0; mi < 2; mi++)
            a[mi] = *(const f16x8*)&h1l[mi*16 + ml][k];
        #pragma unroll
        for (int ni = 0; ni < 4; ni++)
            b[ni] = *(const f16x8*)&iw2t[(size_t)(ni*16 + ml) * 1024 + k];
        #pragma unroll
        for (int mi = 0; mi < 2; mi++)
            #pragma unroll
            for (int ni = 0; ni < 4; ni++)
                a2[mi][ni] = __builtin_amdgcn_mfma_f32_16x16x32_f16(a[mi], b[ni], a2[mi][ni], 0, 0, 0);
    }
    __syncthreads();
    #pragma unroll
    for (int mi = 0; mi < 2; mi++)
        #pragma unroll
        for (int ni = 0; ni < 4; ni++)
            #pragma unroll
            for (int r = 0; r < 4; r++) {
                const int row = mi*16 + q*4 + r;
                const int col = ni*16 + ml;
                red[(size_t)w*2048 + row*64 + col] = a2[mi][ni][r];
            }
    __syncthreads();
    for (int i = t; i < 2048; i += 256) {
        const int row = i >> 6, col = i & 63;
        float s = red[i] + red[2048 + i] + red[4096 + i] + red[6144 + i] + ib2[col];
        seq[(size_t)(bs0 + row) * 64 + col] = s;
    }
}

// ---------- K3: outer attention, MFMA, 1 block/b, 1 wave/head ---------------
__device__ inline void oa_proj_rows(
    const _Float16 (*seqf)[72], const _Float16* __restrict__ wt,
    const float* __restrict__ bias, _Float16 (*dst)[72], int q, int ml)
{
    f32x4 acc[2][4];
    #pragma unroll
    for (int mi = 0; mi < 2; mi++)
        #pragma unroll
        for (int ni = 0; ni < 4; ni++) acc[mi][ni] = (f32x4){0.f,0.f,0.f,0.f};
    #pragma unroll
    for (int k0 = 0; k0 < 64; k0 += 32) {
        f16x8 a[2], bb[4];
        #pragma unroll
        for (int mi = 0; mi < 2; mi++) a[mi] = *(const f16x8*)&seqf[mi*16 + ml][k0 + q*8];
        #pragma unroll
        for (int ni = 0; ni < 4; ni++) bb[ni] = *(const f16x8*)&wt[(size_t)(ni*16 + ml)*64 + k0 + q*8];
        #pragma unroll
        for (int mi = 0; mi < 2; mi++)
            #pragma unroll
            for (int ni = 0; ni < 4; ni++)
                acc[mi][ni] = __builtin_amdgcn_mfma_f32_16x16x32_f16(a[mi], bb[ni], acc[mi][ni], 0, 0, 0);
    }
    #pragma unroll
    for (int ni = 0; ni < 4; ni++) {
        const float bi = bias[ni*16 + ml];
        #pragma unroll
        for (int mi = 0; mi < 2; mi++)
            #pragma unroll
            for (int r = 0; r < 4; r++)
                dst[mi*16 + q*4 + r][ni*16 + ml] = (_Float16)(acc[mi][ni][r] + bi);
    }
}

__device__ inline void oa_proj_t(
    const _Float16 (*seqf)[72], const _Float16* __restrict__ wt,
    const float* __restrict__ bias, _Float16 (*dstT)[40], int q, int ml)
{
    f32x4 acc[2][4];
    #pragma unroll
    for (int mi = 0; mi < 2; mi++)
        #pragma unroll
        for (int ni = 0; ni < 4; ni++) acc[mi][ni] = (f32x4){0.f,0.f,0.f,0.f};
    #pragma unroll
    for (int k0 = 0; k0 < 64; k0 += 32) {
        f16x8 a[2], bb[4];
        #pragma unroll
        for (int mi = 0; mi < 2; mi++) a[mi] = *(const f16x8*)&seqf[mi*16 + ml][k0 + q*8];
        #pragma unroll
        for (int ni = 0; ni < 4; ni++) bb[ni] = *(const f16x8*)&wt[(size_t)(ni*16 + ml)*64 + k0 + q*8];
        #pragma unroll
        for (int mi = 0; mi < 2; mi++)
            #pragma unroll
            for (int ni = 0; ni < 4; ni++)
                acc[mi][ni] = __builtin_amdgcn_mfma_f32_16x16x32_f16(a[mi], bb[ni], acc[mi][ni], 0, 0, 0);
    }
    #pragma unroll
    for (int ni = 0; ni < 4; ni++) {
        const float bi = bias[ni*16 + ml];
        #pragma unroll
        for (int mi = 0; mi < 2; mi++)
            #pragma unroll
            for (int r = 0; r < 4; r++)
                dstT[ni*16 + ml][mi*16 + q*4 + r] = (_Float16)(acc[mi][ni][r] + bi);
    }
}

__global__ __launch_bounds__(256) void k_outer_attn_mfma(
    const float* __restrict__ seq,
    const _Float16* __restrict__ owqt,
    const _Float16* __restrict__ owkt,
    const _Float16* __restrict__ owvt,
    const float* __restrict__ obq, const float* __restrict__ obk,
    const float* __restrict__ obv,
    _Float16* __restrict__ ctxo)
{
    __shared__ __align__(16) _Float16 seqf[32][72];
    __shared__ __align__(16) _Float16 qf[4][32][72];
    __shared__ __align__(16) _Float16 kf[4][32][72];
    __shared__ __align__(16) _Float16 vt[4][64][40];
    __shared__ __align__(16) _Float16 pf[4][32][40];
    const int t = threadIdx.x, lane = t & 63, w = t >> 6;
    const int q = lane >> 4, ml = lane & 15;
    const int b = blockIdx.x;

    const float* sb = seq + (size_t)b * 1920;
    for (int i = t; i < 2048; i += 256) {
        const int row = i >> 6, col = i & 63;
        seqf[row][col] = (_Float16)(row < 30 ? sb[row*64 + col] : 0.0f);
    }
    __syncthreads();

    oa_proj_rows(seqf, owqt + w*4096, obq + w*64, qf[w], q, ml);
    oa_proj_rows(seqf, owkt + w*4096, obk + w*64, kf[w], q, ml);
    oa_proj_t   (seqf, owvt + w*4096, obv + w*64, vt[w], q, ml);
    __syncthreads();

    f32x4 sc[2][2];
    #pragma unroll
    for (int mi = 0; mi < 2; mi++)
        #pragma unroll
        for (int ni = 0; ni < 2; ni++) sc[mi][ni] = (f32x4){0.f,0.f,0.f,0.f};
    #pragma unroll
    for (int k0 = 0; k0 < 64; k0 += 32) {
        f16x8 aq[2], bk[2];
        #pragma unroll
        for (int mi = 0; mi < 2; mi++) aq[mi] = *(const f16x8*)&qf[w][mi*16 + ml][k0 + q*8];
        #pragma unroll
        for (int ni = 0; ni < 2; ni++) bk[ni] = *(const f16x8*)&kf[w][ni*16 + ml][k0 + q*8];
        #pragma unroll
        for (int mi = 0; mi < 2; mi++)
            #pragma unroll
            for (int ni = 0; ni < 2; ni++)
                sc[mi][ni] = __builtin_amdgcn_mfma_f32_16x16x32_f16(aq[mi], bk[ni], sc[mi][ni], 0, 0, 0);
    }

    const bool maskhi = (ml >= 14);
    #pragma unroll
    for (int mi = 0; mi < 2; mi++) {
        #pragma unroll
        for (int r = 0; r < 4; r++) {
            const float s0 = sc[mi][0][r] * 0.125f;
            const float s1 = maskhi ? -1e30f : sc[mi][1][r] * 0.125f;
            float mx = fmaxf(s0, s1);
            #pragma unroll
            for (int off = 1; off < 16; off <<= 1) mx = fmaxf(mx, __shfl_xor(mx, off, 64));
            const float e0 = __expf(s0 - mx);
            const float e1 = __expf(s1 - mx);
            float sm = e0 + e1;
            #pragma unroll
            for (int off = 1; off < 16; off <<= 1) sm += __shfl_xor(sm, off, 64);
            const float inv = 1.0f / sm;
            pf[w][mi*16 + q*4 + r][ml]      = (_Float16)(e0 * inv);
            pf[w][mi*16 + q*4 + r][16 + ml] = (_Float16)(e1 * inv);
        }
    }
    __syncthreads();

    f16x8 ap[2], bv[4];
    #pragma unroll
    for (int mi = 0; mi < 2; mi++) ap[mi] = *(const f16x8*)&pf[w][mi*16 + ml][q*8];
    #pragma unroll
    for (int ni = 0; ni < 4; ni++) bv[ni] = *(const f16x8*)&vt[w][ni*16 + ml][q*8];
    f32x4 oa[2][4];
    #pragma unroll
    for (int mi = 0; mi < 2; mi++)
        #pragma unroll
        for (int ni = 0; ni < 4; ni++) {
            oa[mi][ni] = (f32x4){0.f,0.f,0.f,0.f};
            oa[mi][ni] = __builtin_amdgcn_mfma_f32_16x16x32_f16(ap[mi], bv[ni], oa[mi][ni], 0, 0, 0);
        }

    _Float16* co = ctxo + (size_t)(b*4 + w) * 1920;
    #pragma unroll
    for (int mi = 0; mi < 2; mi++)
        #pragma unroll
        for (int r = 0; r < 4; r++) {
            const int row = mi*16 + q*4 + r;
            if (row < 30) {
                #pragma unroll
                for (int ni = 0; ni < 4; ni++)
                    co[row*64 + ni*16 + ml] = (_Float16)oa[mi][ni][r];
            }
        }
}

// ---------- G3: outer fc1  [4096][1024] = ctxo x ow1t, tanh -> f16 ----------
// 512 blocks x 4 waves; block tile 128x64 = 2 M-halves x (2-way K-split);
// per-wave stream identical to R8 (64x64 out, K=960, 30 iters, depth-2 ring)
__global__ __launch_bounds__(256) void k_outer_fc1_mfma(
    const _Float16* __restrict__ ctxo,   // [4096][1920]
    const _Float16* __restrict__ ow1t,   // [1024][1920]
    const float* __restrict__ ob1,
    _Float16* __restrict__ hout)         // [4096][1024]
{
    __shared__ float red[2][64][65];     // 33.3 KB; red[mhalf]
    const int t = threadIdx.x, lane = t & 63, w = t >> 6;
    const int q = lane >> 4, ml = lane & 15;
    const int mh = w >> 1, kh = w & 1;
    const int Mb = (blockIdx.x >> 4) * 128;  // 32 M-blocks
    const int M0 = Mb + mh * 64;
    const int N0 = (blockIdx.x & 15) * 64;   // 16 N-tiles
    const int kk0 = kh * 960 + q * 8;
    f32x4 acc[4][4];
    #pragma unroll
    for (int mi = 0; mi < 4; mi++)
        #pragma unroll
        for (int ni = 0; ni < 4; ni++) acc[mi][ni] = (f32x4){0.f,0.f,0.f,0.f};
    f16x8 a[2][4], b[2][4];
    #pragma unroll
    for (int mi = 0; mi < 4; mi++)
        a[0][mi] = *(const f16x8*)&ctxo[(size_t)(M0 + mi*16 + ml) * 1920 + kk0];
    #pragma unroll
    for (int ni = 0; ni < 4; ni++)
        b[0][ni] = *(const f16x8*)&ow1t[(size_t)(N0 + ni*16 + ml) * 1920 + kk0];
    #pragma unroll
    for (int ks = 0; ks < 30; ks++) {
        const int cur = ks & 1, nxt = cur ^ 1;
        if (ks < 29) {
            const int kn = kk0 + (ks + 1) * 32;
            #pragma unroll
            for (int mi = 0; mi < 4; mi++)
                a[nxt][mi] = *(const f16x8*)&ctxo[(size_t)(M0 + mi*16 + ml) * 1920 + kn];
            #pragma unroll
            for (int ni = 0; ni < 4; ni++)
                b[nxt][ni] = *(const f16x8*)&ow1t[(size_t)(N0 + ni*16 + ml) * 1920 + kn];
        }
        #pragma unroll
        for (int mi = 0; mi < 4; mi++)
            #pragma unroll
            for (int ni = 0; ni < 4; ni++)
                acc[mi][ni] = __builtin_amdgcn_mfma_f32_16x16x32_f16(a[cur][mi], b[cur][ni], acc[mi][ni], 0, 0, 0);
    }
    // k-half 1 publishes, then k-half 0 accumulates in place
    if (kh == 1) {
        #pragma unroll
        for (int mi = 0; mi < 4; mi++)
            #pragma unroll
            for (int ni = 0; ni < 4; ni++)
                #pragma unroll
                for (int r = 0; r < 4; r++)
                    red[mh][mi*16 + q*4 + r][ni*16 + ml] = acc[mi][ni][r];
    }
    __syncthreads();
    if (kh == 0) {
        #pragma unroll
        for (int mi = 0; mi < 4; mi++)
            #pragma unroll
            for (int ni = 0; ni < 4; ni++)
                #pragma unroll
                for (int r = 0; r < 4; r++)
                    red[mh][mi*16 + q*4 + r][ni*16 + ml] += acc[mi][ni][r];
    }
    __syncthreads();
    for (int i = t; i < 8192; i += 256) {
        const int row = i >> 6, col = i & 63;
        const float s = red[row >> 6][row & 63][col] + ob1[N0 + col];
        hout[(size_t)(Mb + row) * 1024 + N0 + col] = (_Float16)tanh_fast(s);
    }
}

// ---------- G4a: outer fc2 main, block-level K-split-4 ----------------------
// 2176 blocks x 4 waves; tile 32x64; block kc in [0,4); wave K=256; prefetch
__global__ __launch_bounds__(256) void k_outer_fc2_mfma(
    const _Float16* __restrict__ hout,   // [1024][4096]
    const _Float16* __restrict__ ow2t,   // [1088][4096]
    float* __restrict__ part)            // [4][1024][1080]
{
    __shared__ float red[4][32][65];
    const int t = threadIdx.x, lane = t & 63, w = t >> 6;
    const int q = lane >> 4, ml = lane & 15;
    const int bid = blockIdx.x;
    const int kc = bid & 3;
    const int rest = bid >> 2;
    const int M0 = (rest / 17) * 32;
    const int N0 = (rest % 17) * 64;
    const int kk0 = kc * 1024 + w * 256 + q * 8;
    f32x4 acc[2][4];
    #pragma unroll
    for (int mi = 0; mi < 2; mi++)
        #pragma unroll
        for (int ni = 0; ni < 4; ni++) acc[mi][ni] = (f32x4){0.f,0.f,0.f,0.f};
    f16x8 a[2][2], b[2][4];
    #pragma unroll
    for (int mi = 0; mi < 2; mi++)
        a[0][mi] = *(const f16x8*)&hout[(size_t)(M0 + mi*16 + ml) * 4096 + kk0];
    #pragma unroll
    for (int ni = 0; ni < 4; ni++)
        b[0][ni] = *(const f16x8*)&ow2t[(size_t)(N0 + ni*16 + ml) * 4096 + kk0];
    #pragma unroll
    for (int ks = 0; ks < 8; ks++) {
        const int cur = ks & 1, nxt = cur ^ 1;
        if (ks < 7) {
            const int kn = kk0 + (ks + 1) * 32;
            #pragma unroll
            for (int mi = 0; mi < 2; mi++)
                a[nxt][mi] = *(const f16x8*)&hout[(size_t)(M0 + mi*16 + ml) * 4096 + kn];
            #pragma unroll
            for (int ni = 0; ni < 4; ni++)
                b[nxt][ni] = *(const f16x8*)&ow2t[(size_t)(N0 + ni*16 + ml) * 4096 + kn];
        }
        #pragma unroll
        for (int mi = 0; mi < 2; mi++)
            #pragma unroll
            for (int ni = 0; ni < 4; ni++)
                acc[mi][ni] = __builtin_amdgcn_mfma_f32_16x16x32_f16(a[cur][mi], b[cur][ni], acc[mi][ni], 0, 0, 0);
    }
    #pragma unroll
    for (int mi = 0; mi < 2; mi++)
        #pragma unroll
        for (int ni = 0; ni < 4; ni++)
            #pragma unroll
            for (int r = 0; r < 4; r++)
                red[w][mi*16 + q*4 + r][ni*16 + ml] = acc[mi][ni][r];
    __syncthreads();
    for (int i = t; i < 2048; i += 256) {
        const int row = i >> 6, col = i & 63;
        const int n = N0 + col;
        if (n < 1080) {
            const float s = red[0][row][col] + red[1][row][col] + red[2][row][col] + red[3][row][col];
            part[(size_t)kc * 1105920 + (size_t)(M0 + row) * 1080 + n] = s;
        }
    }
}

// ---------- G4b: fc2 reduce + bias ------------------------------------------
__global__ __launch_bounds__(256) void k_fc2_reduce(
    const float* __restrict__ part, const float* __restrict__ ob2,
    float* __restrict__ out)
{
    const int idx = blockIdx.x * 256 + threadIdx.x;
    if (idx >= 1105920) return;
    const int n = idx % 1080;
    out[idx] = part[idx] + part[1105920 + idx] + part[2211840 + idx]
             + part[3317760 + idx] + ob2[n];
}

extern "C" void kernel_launch(void* const* d_in, const int* in_sizes, int n_in,
                              void* d_out, int out_size, void* d_ws, size_t ws_size,
                              hipStream_t stream) {
    const float* x   = (const float*)d_in[0];
    const float* iwq = (const float*)d_in[1];
    const float* ibq = (const float*)d_in[2];
    const float* iwk = (const float*)d_in[3];
    const float* ibk = (const float*)d_in[4];
    const float* iwv = (const float*)d_in[5];
    const float* ibv = (const float*)d_in[6];
    const float* iw1 = (const float*)d_in[7];
    const float* ib1 = (const float*)d_in[8];
    const float* iw2 = (const float*)d_in[9];
    const float* ib2 = (const float*)d_in[10];
    const float* owq = (const float*)d_in[11];
    const float* obq = (const float*)d_in[12];
    const float* owk = (const float*)d_in[13];
    const float* obk = (const float*)d_in[14];
    const float* owv = (const float*)d_in[15];
    const float* obv = (const float*)d_in[16];
    const float* ow1 = (const float*)d_in[17];
    const float* ob1 = (const float*)d_in[18];
    const float* ow2 = (const float*)d_in[19];
    const float* ob2 = (const float*)d_in[20];

    char* ws = (char*)d_ws;
    _Float16* iw1t   = (_Float16*)(ws + 0);          // [256][160]
    _Float16* wqf    = (_Float16*)(ws + 98304);      // [64][8]
    _Float16* wkf    = (_Float16*)(ws + 99328);
    _Float16* wvf    = (_Float16*)(ws + 100352);
    _Float16* iw2t   = (_Float16*)(ws + 163840);     // [64][1024]
    _Float16* ow1t   = (_Float16*)(ws + 294912);     // [1024][1920]
    _Float16* ow2t   = (_Float16*)(ws + 4227072);    // [1088][4096]
    _Float16* flat   = (_Float16*)(ws + 13139968);   // [122880][160]
    float*    seq    = (float*)   (ws + 52461568);   // [30720][64]
    _Float16* owqt   = (_Float16*)(ws + 60325888);   // [4][64][64]
    _Float16* owkt   = (_Float16*)(ws + 60358656);
    _Float16* owvt   = (_Float16*)(ws + 60391424);
    _Float16* ctxo   = (_Float16*)(ws + 13139968);   // reuse (dead flat)
    float*    part2  = (float*)   (ws + 13139968);   // fc2 partials (dead ctxo), 17.7MB
    _Float16* houtb  = (_Float16*)(ws + 40000000);   // inside dead flat region
    float*    out    = (float*)d_out;

    k_prep_all       <<<dim3(1937), dim3(256), 0, stream>>>(
        iwq, ibq, iwk, ibk, iwv, ibv, iw1, iw2, ow1, ow2, owq, owk, owv,
        wqf, wkf, wvf, iw1t, iw2t, ow1t, ow2t, owqt, owkt, owvt);
    k_inner_attn_mfma<<<dim3(7680), dim3(256), 0, stream>>>(x, wqf, wkf, wvf, flat);
    k_inner_ml_mfma  <<<dim3(960),  dim3(256), 0, stream>>>(flat, iw1t, iw2t, ib1, ib2, seq);
    k_outer_attn_mfma<<<dim3(1024), dim3(256), 0, stream>>>(seq, owqt, owkt, owvt, obq, obk, obv, ctxo);
    k_outer_fc1_mfma <<<dim3(512),  dim3(256), 0, stream>>>(ctxo, ow1t, ob1, houtb);
    k_outer_fc2_mfma <<<dim3(2176), dim3(256), 0, stream>>>(houtb, ow2t, part2);
    k_fc2_reduce     <<<dim3(4320), dim3(256), 0, stream>>>(part2, ob2, out);
}

// Round 13
// 317.274 us; speedup vs baseline: 1.1698x; 1.0658x over previous
//
#include <hip/hip_runtime.h>

// DoubleAttention: B=1024, S_OUT=30, S_IN=17, D_IN=3, H=4
// Round 13: fc1 rewritten m97-style: global_load_lds (16B) staging into LDS,
// 128x64 tile, BK=32, 2-barrier K-loop, grid 512 (2 blocks/CU). Evidence:
// five register-path fc1 shapes all pinned at ~1 TB/s fetch / <=9% MfmaUtil
// with compiler-elided prefetch; guide m93->m97 shows async LDS staging is
// the structural fix (fire-and-forget loads, no VGPR hazard).
//
// ws map (bytes) [R8 layout]:
//   iw1t @0  wq/wk/wvf @98304..  iw2t @163840  ow1t @294912  ow2t @4227072
//   flat @13139968 (39.3MB, dead after inner_ml)
//   seq  @52461568  owqt/owkt/owvt @60325888..60424192
//   ctxo @13139968 (reuse; dead after fc1)
//   part2 @13139968 (reuse; fc2 partials f32 [4][1024][1080], 17.7MB)
//   hout @40000000 ([1024][4096] f16, 8.4MB; inside dead flat region)

typedef _Float16 f16x8 __attribute__((ext_vector_type(8)));
typedef _Float16 f16x4 __attribute__((ext_vector_type(4)));
typedef float    f32x4 __attribute__((ext_vector_type(4)));
typedef float    f32x16 __attribute__((ext_vector_type(16)));

union F16x8u { f16x8 v; f16x4 q[2]; };

typedef __attribute__((address_space(1))) const unsigned int as1_u32;
typedef __attribute__((address_space(3))) unsigned int as3_u32;

// async global->LDS, 16B per lane; LDS dest = wave-uniform base + lane*16
__device__ inline void gl_lds16(const _Float16* g, _Float16* l) {
    __builtin_amdgcn_global_load_lds((as1_u32*)g, (as3_u32*)l, 16, 0, 0);
}

__device__ inline float tanh_fast(float x) {
    float ax = fabsf(x);
    float e  = __expf(2.0f * ax);
    float r  = 1.0f - 2.0f / (e + 1.0f);
    return copysignf(r, x);
}

__device__ inline f32x16 zero16() {
    f32x16 z;
    #pragma unroll
    for (int i = 0; i < 16; i++) z[i] = 0.f;
    return z;
}

// ---------- merged prep: frags + all transposes in ONE dispatch -------------
__device__ inline void tcast_tile(
    const float* __restrict__ W, _Float16* __restrict__ Wt,
    int tileIdx, int nkx, int K, int N, int Kpad,
    _Float16 (*tile)[65], int t)
{
    const int kx = tileIdx % nkx, ny = tileIdx / nkx;
    const int k0 = kx * 64, n0 = ny * 64;
    for (int i = t; i < 4096; i += 256) {
        const int r = i >> 6, c = i & 63;
        const int k = k0 + r, n = n0 + c;
        float v = (k < K && n < N) ? W[(size_t)k * N + n] : 0.f;
        tile[c][r] = (_Float16)v;
    }
    __syncthreads();
    for (int i = t; i < 4096; i += 256) {
        const int r = i >> 6, c = i & 63;
        Wt[(size_t)(n0 + r) * Kpad + k0 + c] = tile[r][c];
    }
}

__global__ __launch_bounds__(256) void k_prep_all(
    const float* __restrict__ iwq, const float* __restrict__ ibq,
    const float* __restrict__ iwk, const float* __restrict__ ibk,
    const float* __restrict__ iwv, const float* __restrict__ ibv,
    const float* __restrict__ iw1, const float* __restrict__ iw2,
    const float* __restrict__ ow1, const float* __restrict__ ow2,
    const float* __restrict__ owq, const float* __restrict__ owk,
    const float* __restrict__ owv,
    _Float16* __restrict__ wqf, _Float16* __restrict__ wkf,
    _Float16* __restrict__ wvf,
    _Float16* __restrict__ iw1t, _Float16* __restrict__ iw2t,
    _Float16* __restrict__ ow1t, _Float16* __restrict__ ow2t,
    _Float16* __restrict__ owqt, _Float16* __restrict__ owkt,
    _Float16* __restrict__ owvt)
{
    __shared__ _Float16 tile[64][65];
    const int b = blockIdx.x, t = threadIdx.x;
    if (b == 0) {
        const float SC = 0.40824829046386307f;   // 1/sqrt(6) folded into Q
        for (int i = t; i < 512; i += 256) {
            const int lanev = i >> 3, jj = i & 7;
            const int n = lanev & 31, grp = lanev >> 5;
            const int h = n >> 3, dk = n & 7;
            float q = 0.f, k = 0.f, v = 0.f;
            if (!grp) {
                if (jj < 3) {
                    if (dk < 6) { q = iwq[h*18 + jj*6 + dk] * SC; k = iwk[h*18 + jj*6 + dk]; }
                    v = iwv[h*24 + jj*8 + dk];
                } else if (jj == 3) {
                    if (dk < 6) { q = ibq[h*6 + dk] * SC; k = ibk[h*6 + dk]; }
                    v = ibv[h*8 + dk];
                }
            }
            wqf[i] = (_Float16)q; wkf[i] = (_Float16)k; wvf[i] = (_Float16)v;
        }
    } else if (b < 161) {
        const int idx = (b - 1) * 256 + t;        // 40960 = 256n x 160k'
        if (idx < 40960) {
            const int n = idx / 160, kp = idx - n * 160;
            const int dv = kp / 20, p = kp - dv * 20;
            float v = (p < 17) ? iw1[(p*8 + dv) * 256 + n] : 0.f;
            iw1t[n * 160 + kp] = (_Float16)v;
        }
    } else if (b < 177) {
        tcast_tile(iw2, iw2t, b - 161, 16, 1024, 64, 1024, tile, t);
    } else if (b < 657) {
        tcast_tile(ow1, ow1t, b - 177, 30, 1920, 1024, 1920, tile, t);
    } else if (b < 1745) {
        tcast_tile(ow2, ow2t, b - 657, 64, 4096, 1080, 4096, tile, t);
    } else {
        const int s = b - 1745;                    // 192 = 3 mats x 4 h x 16
        const int mat = s >> 6, rem = s & 63;
        const int h = rem >> 4, blk = rem & 15;
        const int idx = blk * 256 + t;
        const int n = idx >> 6, k = idx & 63;
        const float* W = (mat == 0) ? owq : (mat == 1) ? owk : owv;
        _Float16* Wt   = (mat == 0) ? owqt : (mat == 1) ? owkt : owvt;
        Wt[h * 4096 + n * 64 + k] = (_Float16)W[h * 4096 + k * 64 + n];
    }
}

// ---------- K1: inner attention, MFMA, 1 wave per (b,s) ---------------------
__global__ __launch_bounds__(256, 3) void k_inner_attn_mfma(
    const float* __restrict__ x,
    const _Float16* __restrict__ wqf, const _Float16* __restrict__ wkf,
    const _Float16* __restrict__ wvf,
    _Float16* __restrict__ flat)
{
    __shared__ __align__(16) _Float16 lds[4][5248];
    const int t = threadIdx.x, lane = t & 63, w = t >> 6;
    const int l31 = lane & 31, grp = lane >> 5;
    const int bs = blockIdx.x * 4 + w;
    _Float16* kq  = &lds[w][0];
    _Float16* qq  = &lds[w][1152];
    _Float16* vt  = &lds[w][2304];
    _Float16* pf  = &lds[w][3456];
    _Float16* fo2 = &lds[w][4608];

    f16x8 xf;
    #pragma unroll
    for (int i = 0; i < 8; i++) xf[i] = (_Float16)0.f;
    if (grp == 0 && l31 < 17) {
        const float* xr = x + (size_t)bs * 51 + l31 * 3;
        xf[0] = (_Float16)xr[0];
        xf[1] = (_Float16)xr[1];
        xf[2] = (_Float16)xr[2];
        xf[3] = (_Float16)1.0f;
    }
    const f16x8 wq8 = *(const f16x8*)&wqf[lane * 8];
    const f16x8 wk8 = *(const f16x8*)&wkf[lane * 8];
    const f16x8 wv8 = *(const f16x8*)&wvf[lane * 8];

    f32x16 kt = __builtin_amdgcn_mfma_f32_32x32x16_f16(wk8, xf, zero16(), 0, 0, 0);
    f32x16 qt = __builtin_amdgcn_mfma_f32_32x32x16_f16(wq8, xf, zero16(), 0, 0, 0);
    f32x16 vv = __builtin_amdgcn_mfma_f32_32x32x16_f16(xf, wv8, zero16(), 0, 0, 0);

    #pragma unroll
    for (int qd = 0; qd < 4; qd++) {
        const int base = 8 * qd + 4 * grp;
        f16x4 a, b, c;
        #pragma unroll
        for (int i = 0; i < 4; i++) {
            a[i] = (_Float16)kt[4*qd + i];
            b[i] = (_Float16)qt[4*qd + i];
            c[i] = (_Float16)vv[4*qd + i];
        }
        *(f16x4*)&kq[l31 * 36 + base] = a;   // kq[j][n]
        *(f16x4*)&qq[l31 * 36 + base] = b;   // qq[p][n]
        *(f16x4*)&vt[l31 * 36 + base] = c;   // vt[n][j]
    }

    #pragma unroll
    for (int h = 0; h < 4; h++) {
        F16x8u ka, qb;
        #pragma unroll
        for (int i = 0; i < 8; i++) { ka.v[i] = (_Float16)0.f; qb.v[i] = (_Float16)0.f; }
        if (grp == 0) {
            ka.q[0] = *(const f16x4*)&kq[l31 * 36 + h * 8];
            ka.q[1] = *(const f16x4*)&kq[l31 * 36 + h * 8 + 4];
            qb.q[0] = *(const f16x4*)&qq[l31 * 36 + h * 8];
            qb.q[1] = *(const f16x4*)&qq[l31 * 36 + h * 8 + 4];
        }
        f32x16 s = __builtin_amdgcn_mfma_f32_32x32x16_f16(ka.v, qb.v, zero16(), 0, 0, 0);

        float mx = -1e30f;
        #pragma unroll
        for (int r = 0; r < 16; r++) {
            const bool val = (r < 8) || (r == 8 && grp == 0);
            if (val) mx = fmaxf(mx, s[r]);
        }
        mx = fmaxf(mx, __shfl_xor(mx, 32));
        float e[16], sum = 0.f;
        #pragma unroll
        for (int r = 0; r < 16; r++) {
            const bool val = (r < 8) || (r == 8 && grp == 0);
            e[r] = val ? __expf(s[r] - mx) : 0.f;
            sum += e[r];
        }
        sum += __shfl_xor(sum, 32);
        const float inv = __builtin_amdgcn_rcpf(sum);
        #pragma unroll
        for (int qd = 0; qd < 4; qd++) {
            f16x4 pk;
            #pragma unroll
            for (int i = 0; i < 4; i++) pk[i] = (_Float16)(e[4*qd + i] * inv);
            *(f16x4*)&pf[l31 * 36 + 8 * qd + 4 * grp] = pk;   // pf[p][j]
        }

        F16x8u pa1, pa2, vb1, vb2;
        pa1.q[0] = *(const f16x4*)&pf[l31 * 36 + grp * 8];
        pa1.q[1] = *(const f16x4*)&pf[l31 * 36 + grp * 8 + 4];
        pa2.q[0] = *(const f16x4*)&pf[l31 * 36 + 16 + grp * 8];
        pa2.q[1] = *(const f16x4*)&pf[l31 * 36 + 16 + grp * 8 + 4];
        const int vr = (h * 8 + (l31 & 7)) * 36;
        vb1.q[0] = *(const f16x4*)&vt[vr + grp * 8];
        vb1.q[1] = *(const f16x4*)&vt[vr + grp * 8 + 4];
        vb2.q[0] = *(const f16x4*)&vt[vr + 16 + grp * 8];
        vb2.q[1] = *(const f16x4*)&vt[vr + 16 + grp * 8 + 4];
        f32x16 c = __builtin_amdgcn_mfma_f32_32x32x16_f16(pa1.v, vb1.v, zero16(), 0, 0, 0);
        c = __builtin_amdgcn_mfma_f32_32x32x16_f16(pa2.v, vb2.v, c, 0, 0, 0);

        if (l31 < 8) {
            #pragma unroll
            for (int qd = 0; qd < 4; qd++) {
                const int jb = 8 * qd + 4 * grp;
                if (jb < 20) {
                    f16x4 ck;
                    #pragma unroll
                    for (int i = 0; i < 4; i++) ck[i] = (_Float16)c[4*qd + i];
                    *(f16x4*)&fo2[h * 160 + l31 * 20 + jb] = ck;
                }
            }
        }
    }

    _Float16* fg = flat + (size_t)bs * 640;
    *(f16x8*)&fg[lane * 8] = *(const f16x8*)&fo2[lane * 8];
    if (lane < 16)
        *(f16x8*)&fg[512 + lane * 8] = *(const f16x8*)&fo2[512 + lane * 8];
}

// ---------- G12: inner ML fused (fc1+tanh -> LDS -> fc2), MFMA --------------
__global__ __launch_bounds__(256) void k_inner_ml_mfma(
    const _Float16* __restrict__ flat,   // [122880][160] (k'=dv*20+p)
    const _Float16* __restrict__ iw1t,   // [256][160]
    const _Float16* __restrict__ iw2t,   // [64][1024]
    const float* __restrict__ ib1, const float* __restrict__ ib2,
    float* __restrict__ seq)             // [30720][64]
{
    __shared__ __align__(16) _Float16 h1l[32][1032];
    float* red = (float*)&h1l[0][0];
    const int t = threadIdx.x, lane = t & 63, w = t >> 6;
    const int q = lane >> 4, ml = lane & 15;
    const int m0  = blockIdx.x * 128;
    const int bs0 = blockIdx.x * 32;

    for (int p = 0; p < 2; p++) {
        f32x4 acc[4][4];
        #pragma unroll
        for (int mi = 0; mi < 4; mi++)
            #pragma unroll
            for (int ni = 0; ni < 4; ni++) acc[mi][ni] = (f32x4){0.f,0.f,0.f,0.f};
        for (int ks = 0; ks < 5; ks++) {
            const int k = ks * 32 + q * 8;
            f16x8 a[4], b[4];
            #pragma unroll
            for (int mi = 0; mi < 4; mi++)
                a[mi] = *(const f16x8*)&flat[(size_t)(m0 + p*64 + mi*16 + ml) * 160 + k];
            #pragma unroll
            for (int ni = 0; ni < 4; ni++)
                b[ni] = *(const f16x8*)&iw1t[(size_t)(w*64 + ni*16 + ml) * 160 + k];
            #pragma unroll
            for (int mi = 0; mi < 4; mi++)
                #pragma unroll
                for (int ni = 0; ni < 4; ni++)
                    acc[mi][ni] = __builtin_amdgcn_mfma_f32_16x16x32_f16(a[mi], b[ni], acc[mi][ni], 0, 0, 0);
        }
        #pragma unroll
        for (int mi = 0; mi < 4; mi++)
            #pragma unroll
            for (int ni = 0; ni < 4; ni++)
                #pragma unroll
                for (int r = 0; r < 4; r++) {
                    const int row = p*64 + mi*16 + q*4 + r;
                    const int col = w*64 + ni*16 + ml;
                    const int bs_l = row >> 2, h = row & 3;
                    h1l[bs_l][h*256 + col] = (_Float16)tanh_fast(acc[mi][ni][r] + ib1[col]);
                }
    }
    __syncthreads();

    f32x4 a2[2][4];
    #pragma unroll
    for (int mi = 0; mi < 2; mi++)
        #pragma unroll
        for (int ni = 0; ni < 4; ni++) a2[mi][ni] = (f32x4){0.f,0.f,0.f,0.f};
    for (int ks = 0; ks < 8; ks++) {
        const int k = w * 256 + ks * 32 + q * 8;
        f16x8 a[2], b[4];
        #pragma unroll
        for (int mi = 0; mi < 2; mi++)
            a[mi] = *(const f16x8*)&h1l[mi*16 + ml][k];
        #pragma unroll
        for (int ni = 0; ni < 4; ni++)
            b[ni] = *(const f16x8*)&iw2t[(size_t)(ni*16 + ml) * 1024 + k];
        #pragma unroll
        for (int mi = 0; mi < 2; mi++)
            #pragma unroll
            for (int ni = 0; ni < 4; ni++)
                a2[mi][ni] = __builtin_amdgcn_mfma_f32_16x16x32_f16(a[mi], b[ni], a2[mi][ni], 0, 0, 0);
    }
    __syncthreads();
    #pragma unroll
    for (int mi = 0; mi < 2; mi++)
        #pragma unroll
        for (int ni = 0; ni < 4; ni++)
            #pragma unroll
            for (int r = 0; r < 4; r++) {
                const int row = mi*16 + q*4 + r;
                const int col = ni*16 + ml;
                red[(size_t)w*2048 + row*64 + col] = a2[mi][ni][r];
            }
    __syncthreads();
    for (int i = t; i < 2048; i += 256) {
        const int row = i >> 6, col = i & 63;
        float s = red[i] + red[2048 + i] + red[4096 + i] + red[6144 + i] + ib2[col];
        seq[(size_t)(bs0 + row) * 64 + col] = s;
    }
}

// ---------- K3: outer attention, MFMA, 1 block/b, 1 wave/head ---------------
__device__ inline void oa_proj_rows(
    const _Float16 (*seqf)[72], const _Float16* __restrict__ wt,
    const float* __restrict__ bias, _Float16 (*dst)[72], int q, int ml)
{
    f32x4 acc[2][4];
    #pragma unroll
    for (int mi = 0; mi < 2; mi++)
        #pragma unroll
        for (int ni = 0; ni < 4; ni++) acc[mi][ni] = (f32x4){0.f,0.f,0.f,0.f};
    #pragma unroll
    for (int k0 = 0; k0 < 64; k0 += 32) {
        f16x8 a[2], bb[4];
        #pragma unroll
        for (int mi = 0; mi < 2; mi++) a[mi] = *(const f16x8*)&seqf[mi*16 + ml][k0 + q*8];
        #pragma unroll
        for (int ni = 0; ni < 4; ni++) bb[ni] = *(const f16x8*)&wt[(size_t)(ni*16 + ml)*64 + k0 + q*8];
        #pragma unroll
        for (int mi = 0; mi < 2; mi++)
            #pragma unroll
            for (int ni = 0; ni < 4; ni++)
                acc[mi][ni] = __builtin_amdgcn_mfma_f32_16x16x32_f16(a[mi], bb[ni], acc[mi][ni], 0, 0, 0);
    }
    #pragma unroll
    for (int ni = 0; ni < 4; ni++) {
        const float bi = bias[ni*16 + ml];
        #pragma unroll
        for (int mi = 0; mi < 2; mi++)
            #pragma unroll
            for (int r = 0; r < 4; r++)
                dst[mi*16 + q*4 + r][ni*16 + ml] = (_Float16)(acc[mi][ni][r] + bi);
    }
}

__device__ inline void oa_proj_t(
    const _Float16 (*seqf)[72], const _Float16* __restrict__ wt,
    const float* __restrict__ bias, _Float16 (*dstT)[40], int q, int ml)
{
    f32x4 acc[2][4];
    #pragma unroll
    for (int mi = 0; mi < 2; mi++)
        #pragma unroll
        for (int ni = 0; ni < 4; ni++) acc[mi][ni] = (f32x4){0.f,0.f,0.f,0.f};
    #pragma unroll
    for (int k0 = 0; k0 < 64; k0 += 32) {
        f16x8 a[2], bb[4];
        #pragma unroll
        for (int mi = 0; mi < 2; mi++) a[mi] = *(const f16x8*)&seqf[mi*16 + ml][k0 + q*8];
        #pragma unroll
        for (int ni = 0; ni < 4; ni++) bb[ni] = *(const f16x8*)&wt[(size_t)(ni*16 + ml)*64 + k0 + q*8];
        #pragma unroll
        for (int mi = 0; mi < 2; mi++)
            #pragma unroll
            for (int ni = 0; ni < 4; ni++)
                acc[mi][ni] = __builtin_amdgcn_mfma_f32_16x16x32_f16(a[mi], bb[ni], acc[mi][ni], 0, 0, 0);
    }
    #pragma unroll
    for (int ni = 0; ni < 4; ni++) {
        const float bi = bias[ni*16 + ml];
        #pragma unroll
        for (int mi = 0; mi < 2; mi++)
            #pragma unroll
            for (int r = 0; r < 4; r++)
                dstT[ni*16 + ml][mi*16 + q*4 + r] = (_Float16)(acc[mi][ni][r] + bi);
    }
}

__global__ __launch_bounds__(256) void k_outer_attn_mfma(
    const float* __restrict__ seq,
    const _Float16* __restrict__ owqt,
    const _Float16* __restrict__ owkt,
    const _Float16* __restrict__ owvt,
    const float* __restrict__ obq, const float* __restrict__ obk,
    const float* __restrict__ obv,
    _Float16* __restrict__ ctxo)
{
    __shared__ __align__(16) _Float16 seqf[32][72];
    __shared__ __align__(16) _Float16 qf[4][32][72];
    __shared__ __align__(16) _Float16 kf[4][32][72];
    __shared__ __align__(16) _Float16 vt[4][64][40];
    __shared__ __align__(16) _Float16 pf[4][32][40];
    const int t = threadIdx.x, lane = t & 63, w = t >> 6;
    const int q = lane >> 4, ml = lane & 15;
    const int b = blockIdx.x;

    const float* sb = seq + (size_t)b * 1920;
    for (int i = t; i < 2048; i += 256) {
        const int row = i >> 6, col = i & 63;
        seqf[row][col] = (_Float16)(row < 30 ? sb[row*64 + col] : 0.0f);
    }
    __syncthreads();

    oa_proj_rows(seqf, owqt + w*4096, obq + w*64, qf[w], q, ml);
    oa_proj_rows(seqf, owkt + w*4096, obk + w*64, kf[w], q, ml);
    oa_proj_t   (seqf, owvt + w*4096, obv + w*64, vt[w], q, ml);
    __syncthreads();

    f32x4 sc[2][2];
    #pragma unroll
    for (int mi = 0; mi < 2; mi++)
        #pragma unroll
        for (int ni = 0; ni < 2; ni++) sc[mi][ni] = (f32x4){0.f,0.f,0.f,0.f};
    #pragma unroll
    for (int k0 = 0; k0 < 64; k0 += 32) {
        f16x8 aq[2], bk[2];
        #pragma unroll
        for (int mi = 0; mi < 2; mi++) aq[mi] = *(const f16x8*)&qf[w][mi*16 + ml][k0 + q*8];
        #pragma unroll
        for (int ni = 0; ni < 2; ni++) bk[ni] = *(const f16x8*)&kf[w][ni*16 + ml][k0 + q*8];
        #pragma unroll
        for (int mi = 0; mi < 2; mi++)
            #pragma unroll
            for (int ni = 0; ni < 2; ni++)
                sc[mi][ni] = __builtin_amdgcn_mfma_f32_16x16x32_f16(aq[mi], bk[ni], sc[mi][ni], 0, 0, 0);
    }

    const bool maskhi = (ml >= 14);
    #pragma unroll
    for (int mi = 0; mi < 2; mi++) {
        #pragma unroll
        for (int r = 0; r < 4; r++) {
            const float s0 = sc[mi][0][r] * 0.125f;
            const float s1 = maskhi ? -1e30f : sc[mi][1][r] * 0.125f;
            float mx = fmaxf(s0, s1);
            #pragma unroll
            for (int off = 1; off < 16; off <<= 1) mx = fmaxf(mx, __shfl_xor(mx, off, 64));
            const float e0 = __expf(s0 - mx);
            const float e1 = __expf(s1 - mx);
            float sm = e0 + e1;
            #pragma unroll
            for (int off = 1; off < 16; off <<= 1) sm += __shfl_xor(sm, off, 64);
            const float inv = 1.0f / sm;
            pf[w][mi*16 + q*4 + r][ml]      = (_Float16)(e0 * inv);
            pf[w][mi*16 + q*4 + r][16 + ml] = (_Float16)(e1 * inv);
        }
    }
    __syncthreads();

    f16x8 ap[2], bv[4];
    #pragma unroll
    for (int mi = 0; mi < 2; mi++) ap[mi] = *(const f16x8*)&pf[w][mi*16 + ml][q*8];
    #pragma unroll
    for (int ni = 0; ni < 4; ni++) bv[ni] = *(const f16x8*)&vt[w][ni*16 + ml][q*8];
    f32x4 oa[2][4];
    #pragma unroll
    for (int mi = 0; mi < 2; mi++)
        #pragma unroll
        for (int ni = 0; ni < 4; ni++) {
            oa[mi][ni] = (f32x4){0.f,0.f,0.f,0.f};
            oa[mi][ni] = __builtin_amdgcn_mfma_f32_16x16x32_f16(ap[mi], bv[ni], oa[mi][ni], 0, 0, 0);
        }

    _Float16* co = ctxo + (size_t)(b*4 + w) * 1920;
    #pragma unroll
    for (int mi = 0; mi < 2; mi++)
        #pragma unroll
        for (int r = 0; r < 4; r++) {
            const int row = mi*16 + q*4 + r;
            if (row < 30) {
                #pragma unroll
                for (int ni = 0; ni < 4; ni++)
                    co[row*64 + ni*16 + ml] = (_Float16)oa[mi][ni][r];
            }
        }
}

// ---------- G3: outer fc1, m97-style async-LDS GEMM -------------------------
// [4096][1024] = ctxo[4096][1920] x ow1t[1024][1920]^T, +bias, tanh -> f16
// 512 blocks (32M x 16N) x 4 waves; tile 128x64; BK=32; 60 iters;
// global_load_lds 16B staging (LDS dest = wave-uniform base + lane*16)
__global__ __launch_bounds__(256) void k_outer_fc1_mfma(
    const _Float16* __restrict__ ctxo,   // [4096][1920]
    const _Float16* __restrict__ ow1t,   // [1024][1920]
    const float* __restrict__ ob1,
    _Float16* __restrict__ hout)         // [4096][1024]
{
    __shared__ __align__(16) _Float16 At[128][32];   // 8 KB
    __shared__ __align__(16) _Float16 Bt[64][32];    // 4 KB
    const int t = threadIdx.x, lane = t & 63, w = t >> 6;
    const int q = lane >> 4, ml = lane & 15;
    const int M0 = (int)(blockIdx.x >> 4) * 128;
    const int N0 = (int)(blockIdx.x & 15) * 64;
    const int wm = (w >> 1) * 64, wn = (w & 1) * 32;   // wave quadrant 64x32

    // staging: lane l covers tile row base+l/4, f16 cols (l%4)*8..+8
    const int lrow = lane >> 2;
    const int lcol = (lane & 3) * 8;
    const _Float16* gA0 = ctxo + (size_t)(M0 + w*32 + lrow) * 1920 + lcol;
    const _Float16* gA1 = gA0 + (size_t)16 * 1920;
    const _Float16* gB0 = ow1t + (size_t)(N0 + w*16 + lrow) * 1920 + lcol;
    _Float16* lA0 = &At[w*32][0];        // wave-uniform LDS bases
    _Float16* lA1 = &At[w*32 + 16][0];
    _Float16* lB0 = &Bt[w*16][0];

    f32x4 acc[4][2];
    #pragma unroll
    for (int mi = 0; mi < 4; mi++)
        #pragma unroll
        for (int ni = 0; ni < 2; ni++) acc[mi][ni] = (f32x4){0.f,0.f,0.f,0.f};

    for (int ks = 0; ks < 60; ks++) {
        const int k0 = ks * 32;
        gl_lds16(gA0 + k0, lA0);
        gl_lds16(gA1 + k0, lA1);
        gl_lds16(gB0 + k0, lB0);
        __syncthreads();                 // drains vmcnt -> tile ready
        f16x8 a[4], b[2];
        #pragma unroll
        for (int mi = 0; mi < 4; mi++)
            a[mi] = *(const f16x8*)&At[wm + mi*16 + ml][q*8];
        #pragma unroll
        for (int ni = 0; ni < 2; ni++)
            b[ni] = *(const f16x8*)&Bt[wn + ni*16 + ml][q*8];
        #pragma unroll
        for (int mi = 0; mi < 4; mi++)
            #pragma unroll
            for (int ni = 0; ni < 2; ni++)
                acc[mi][ni] = __builtin_amdgcn_mfma_f32_16x16x32_f16(a[mi], b[ni], acc[mi][ni], 0, 0, 0);
        __syncthreads();                 // all ds_reads done before overwrite
    }

    #pragma unroll
    for (int ni = 0; ni < 2; ni++) {
        const int col = N0 + wn + ni*16 + ml;
        const float bias = ob1[col];
        #pragma unroll
        for (int mi = 0; mi < 4; mi++)
            #pragma unroll
            for (int r = 0; r < 4; r++) {
                const int row = M0 + wm + mi*16 + q*4 + r;
                hout[(size_t)row * 1024 + col] = (_Float16)tanh_fast(acc[mi][ni][r] + bias);
            }
    }
}

// ---------- G4a: outer fc2 main, block-level K-split-4 ----------------------
// 2176 blocks x 4 waves; tile 32x64; block kc in [0,4); wave K=256; prefetch
__global__ __launch_bounds__(256) void k_outer_fc2_mfma(
    const _Float16* __restrict__ hout,   // [1024][4096]
    const _Float16* __restrict__ ow2t,   // [1088][4096]
    float* __restrict__ part)            // [4][1024][1080]
{
    __shared__ float red[4][32][65];
    const int t = threadIdx.x, lane = t & 63, w = t >> 6;
    const int q = lane >> 4, ml = lane & 15;
    const int bid = blockIdx.x;
    const int kc = bid & 3;
    const int rest = bid >> 2;
    const int M0 = (rest / 17) * 32;
    const int N0 = (rest % 17) * 64;
    const int kk0 = kc * 1024 + w * 256 + q * 8;
    f32x4 acc[2][4];
    #pragma unroll
    for (int mi = 0; mi < 2; mi++)
        #pragma unroll
        for (int ni = 0; ni < 4; ni++) acc[mi][ni] = (f32x4){0.f,0.f,0.f,0.f};
    f16x8 a[2][2], b[2][4];
    #pragma unroll
    for (int mi = 0; mi < 2; mi++)
        a[0][mi] = *(const f16x8*)&hout[(size_t)(M0 + mi*16 + ml) * 4096 + kk0];
    #pragma unroll
    for (int ni = 0; ni < 4; ni++)
        b[0][ni] = *(const f16x8*)&ow2t[(size_t)(N0 + ni*16 + ml) * 4096 + kk0];
    #pragma unroll
    for (int ks = 0; ks < 8; ks++) {
        const int cur = ks & 1, nxt = cur ^ 1;
        if (ks < 7) {
            const int kn = kk0 + (ks + 1) * 32;
            #pragma unroll
            for (int mi = 0; mi < 2; mi++)
                a[nxt][mi] = *(const f16x8*)&hout[(size_t)(M0 + mi*16 + ml) * 4096 + kn];
            #pragma unroll
            for (int ni = 0; ni < 4; ni++)
                b[nxt][ni] = *(const f16x8*)&ow2t[(size_t)(N0 + ni*16 + ml) * 4096 + kn];
        }
        #pragma unroll
        for (int mi = 0; mi < 2; mi++)
            #pragma unroll
            for (int ni = 0; ni < 4; ni++)
                acc[mi][ni] = __builtin_amdgcn_mfma_f32_16x16x32_f16(a[cur][mi], b[cur][ni], acc[mi][ni], 0, 0, 0);
    }
    #pragma unroll
    for (int mi = 0; mi < 2; mi++)
        #pragma unroll
        for (int ni = 0; ni < 4; ni++)
            #pragma unroll
            for (int r = 0; r < 4; r++)
                red[w][mi*16 + q*4 + r][ni*16 + ml] = acc[mi][ni][r];
    __syncthreads();
    for (int i = t; i < 2048; i += 256) {
        const int row = i >> 6, col = i & 63;
        const int n = N0 + col;
        if (n < 1080) {
            const float s = red[0][row][col] + red[1][row][col] + red[2][row][col] + red[3][row][col];
            part[(size_t)kc * 1105920 + (size_t)(M0 + row) * 1080 + n] = s;
        }
    }
}

// ---------- G4b: fc2 reduce + bias ------------------------------------------
__global__ __launch_bounds__(256) void k_fc2_reduce(
    const float* __restrict__ part, const float* __restrict__ ob2,
    float* __restrict__ out)
{
    const int idx = blockIdx.x * 256 + threadIdx.x;
    if (idx >= 1105920) return;
    const int n = idx % 1080;
    out[idx] = part[idx] + part[1105920 + idx] + part[2211840 + idx]
             + part[3317760 + idx] + ob2[n];
}

extern "C" void kernel_launch(void* const* d_in, const int* in_sizes, int n_in,
                              void* d_out, int out_size, void* d_ws, size_t ws_size,
                              hipStream_t stream) {
    const float* x   = (const float*)d_in[0];
    const float* iwq = (const float*)d_in[1];
    const float* ibq = (const float*)d_in[2];
    const float* iwk = (const float*)d_in[3];
    const float* ibk = (const float*)d_in[4];
    const float* iwv = (const float*)d_in[5];
    const float* ibv = (const float*)d_in[6];
    const float* iw1 = (const float*)d_in[7];
    const float* ib1 = (const float*)d_in[8];
    const float* iw2 = (const float*)d_in[9];
    const float* ib2 = (const float*)d_in[10];
    const float* owq = (const float*)d_in[11];
    const float* obq = (const float*)d_in[12];
    const float* owk = (const float*)d_in[13];
    const float* obk = (const float*)d_in[14];
    const float* owv = (const float*)d_in[15];
    const float* obv = (const float*)d_in[16];
    const float* ow1 = (const float*)d_in[17];
    const float* ob1 = (const float*)d_in[18];
    const float* ow2 = (const float*)d_in[19];
    const float* ob2 = (const float*)d_in[20];

    char* ws = (char*)d_ws;
    _Float16* iw1t   = (_Float16*)(ws + 0);          // [256][160]
    _Float16* wqf    = (_Float16*)(ws + 98304);      // [64][8]
    _Float16* wkf    = (_Float16*)(ws + 99328);
    _Float16* wvf    = (_Float16*)(ws + 100352);
    _Float16* iw2t   = (_Float16*)(ws + 163840);     // [64][1024]
    _Float16* ow1t   = (_Float16*)(ws + 294912);     // [1024][1920]
    _Float16* ow2t   = (_Float16*)(ws + 4227072);    // [1088][4096]
    _Float16* flat   = (_Float16*)(ws + 13139968);   // [122880][160]
    float*    seq    = (float*)   (ws + 52461568);   // [30720][64]
    _Float16* owqt   = (_Float16*)(ws + 60325888);   // [4][64][64]
    _Float16* owkt   = (_Float16*)(ws + 60358656);
    _Float16* owvt   = (_Float16*)(ws + 60391424);
    _Float16* ctxo   = (_Float16*)(ws + 13139968);   // reuse (dead flat)
    float*    part2  = (float*)   (ws + 13139968);   // fc2 partials (dead ctxo), 17.7MB
    _Float16* houtb  = (_Float16*)(ws + 40000000);   // inside dead flat region
    float*    out    = (float*)d_out;

    k_prep_all       <<<dim3(1937), dim3(256), 0, stream>>>(
        iwq, ibq, iwk, ibk, iwv, ibv, iw1, iw2, ow1, ow2, owq, owk, owv,
        wqf, wkf, wvf, iw1t, iw2t, ow1t, ow2t, owqt, owkt, owvt);
    k_inner_attn_mfma<<<dim3(7680), dim3(256), 0, stream>>>(x, wqf, wkf, wvf, flat);
    k_inner_ml_mfma  <<<dim3(960),  dim3(256), 0, stream>>>(flat, iw1t, iw2t, ib1, ib2, seq);
    k_outer_attn_mfma<<<dim3(1024), dim3(256), 0, stream>>>(seq, owqt, owkt, owvt, obq, obk, obv, ctxo);
    k_outer_fc1_mfma <<<dim3(512),  dim3(256), 0, stream>>>(ctxo, ow1t, ob1, houtb);
    k_outer_fc2_mfma <<<dim3(2176), dim3(256), 0, stream>>>(houtb, ow2t, part2);
    k_fc2_reduce     <<<dim3(4320), dim3(256), 0, stream>>>(part2, ob2, out);
}